// Round 12
// baseline (182.755 us; speedup 1.0000x reference)
//
#include <hip/hip_runtime.h>
#include <hip/hip_bf16.h>
#include <cstdint>

typedef unsigned short u16;
typedef __bf16 bf16_t;
typedef __bf16 bf16x8 __attribute__((ext_vector_type(8)));
typedef float f32x4 __attribute__((ext_vector_type(4)));

#define DM   512
#define DFF  2048
#define NEXP 8

__device__ __forceinline__ u16 f2bf(float f) {
  bf16_t b = (bf16_t)f;
  return __builtin_bit_cast(u16, b);
}
__device__ __forceinline__ uint32_t pack_bf2(float lo, float hi) {
  return (uint32_t)f2bf(lo) | ((uint32_t)f2bf(hi) << 16);
}
__device__ __forceinline__ float gelu_tanh(float x) {
  float x3 = x * x * x;
  float z = 0.7978845608028654f * (x + 0.044715f * x3);
  float az = fabsf(z);
  float e = __expf(2.0f * az);
  float t = 1.0f - 2.0f / (e + 1.0f);
  t = copysignf(t, z);
  return 0.5f * x * (1.0f + t);
}
__device__ __forceinline__ void async16(const u16* g, u16* l) {
  __builtin_amdgcn_global_load_lds((const __attribute__((address_space(1))) void*)g,
                                   (__attribute__((address_space(3))) void*)l, 16, 0, 0);
}

// ---------- transpose tile body: src [R][C] f32 (+e offset) -> dst [C][R] bf16
__device__ __forceinline__ void transpose_tile(const float* __restrict__ s,
                                               u16* __restrict__ d, int R, int C,
                                               int tileIdx) {
  __shared__ u16 tile[64][66];
  int tilesC = C >> 6;
  int bR = (tileIdx / tilesC) << 6;
  int bC = (tileIdx % tilesC) << 6;
  int rr = threadIdx.x >> 4;
  int cc = (threadIdx.x & 15) << 2;
#pragma unroll
  for (int i = 0; i < 4; ++i) {
    int r = (i << 4) + rr;
    float4 v = *(const float4*)(s + (size_t)(bR + r) * C + bC + cc);
    *(uint32_t*)&tile[r][cc]     = pack_bf2(v.x, v.y);
    *(uint32_t*)&tile[r][cc + 2] = pack_bf2(v.z, v.w);
  }
  __syncthreads();
  int c0 = threadIdx.x >> 5;
  int j  = (threadIdx.x & 31) << 1;
#pragma unroll
  for (int i = 0; i < 8; ++i) {
    int c = (i << 3) + c0;
    uint32_t v = (uint32_t)tile[j][c] | ((uint32_t)tile[j + 1][c] << 16);
    *(uint32_t*)(&d[(size_t)(bC + c) * R + bR + j]) = v;
  }
}

// ---------- fused prep: W1 transpose | W2 transpose | router
__global__ void k_prep(const float* __restrict__ W1, u16* __restrict__ W1T,
                       const float* __restrict__ W2, u16* __restrict__ W2T,
                       const float* __restrict__ x, const float* __restrict__ Wr,
                       const float* __restrict__ br, int* __restrict__ sel_idx,
                       float* __restrict__ sel_w, int Ntok) {
  int b = blockIdx.x;
  if (b < 2048) {
    int e = b >> 8, t = b & 255;
    transpose_tile(W1 + (size_t)e * DM * DFF, W1T + (size_t)e * DM * DFF, DM, DFF, t);
    return;
  }
  if (b < 4096) {
    int e = (b - 2048) >> 8, t = (b - 2048) & 255;
    transpose_tile(W2 + (size_t)e * DFF * DM, W2T + (size_t)e * DFF * DM, DFF, DM, t);
    return;
  }
  int rb = b - 4096;
  int wid = threadIdx.x >> 6;
  int lane = threadIdx.x & 63;
  int tok = (rb << 2) + wid;
  if (tok >= Ntok) return;
  const float4* xr = (const float4*)(x + (size_t)tok * DM);
  float4 x0 = xr[lane * 2], x1 = xr[lane * 2 + 1];
  float logit[NEXP];
#pragma unroll
  for (int e = 0; e < NEXP; ++e) {
    const float4* wr = (const float4*)(Wr + e * DM);
    float4 w0 = wr[lane * 2], w1 = wr[lane * 2 + 1];
    float p = x0.x * w0.x + x0.y * w0.y + x0.z * w0.z + x0.w * w0.w
            + x1.x * w1.x + x1.y * w1.y + x1.z * w1.z + x1.w * w1.w;
#pragma unroll
    for (int off = 32; off; off >>= 1) p += __shfl_xor(p, off, 64);
    logit[e] = p + br[e];
  }
  if (lane == 0) {
    float mx = logit[0];
#pragma unroll
    for (int e = 1; e < NEXP; ++e) mx = fmaxf(mx, logit[e]);
    float pr[NEXP];
#pragma unroll
    for (int e = 0; e < NEXP; ++e) pr[e] = __expf(logit[e] - mx);
    int i0 = 0;
#pragma unroll
    for (int e = 1; e < NEXP; ++e) if (pr[e] > pr[i0]) i0 = e;
    int i1 = -1;
#pragma unroll
    for (int e = 0; e < NEXP; ++e) {
      if (e == i0) continue;
      if (i1 < 0 || pr[e] > pr[i1]) i1 = e;
    }
    float s2 = pr[i0] + pr[i1];
    sel_idx[tok * 2]     = i0;
    sel_idx[tok * 2 + 1] = i1;
    sel_w[tok * 2]       = pr[i0] / s2;
    sel_w[tok * 2 + 1]   = pr[i1] / s2;
  }
}

// ---------- scatter (1 block, ballot-based), 256-row tile granularity
__global__ void k_scatter(const int* __restrict__ sel_idx, const float* __restrict__ sel_w,
                          int npairs, int* __restrict__ row_token, float* __restrict__ row_w,
                          int* __restrict__ pos_of, int* __restrict__ tileMeta,
                          int* __restrict__ gMeta) {
  __shared__ int cnt[NEXP], offs[NEXP], cur[NEXP];
  int tid = threadIdx.x;
  int lane = tid & 63;
  if (tid < NEXP) { cnt[tid] = 0; cur[tid] = 0; }
  __syncthreads();
  for (int p = tid; p < npairs; p += blockDim.x) {
    int e = sel_idx[p];
#pragma unroll
    for (int ex = 0; ex < NEXP; ++ex) {
      unsigned long long m = __ballot(e == ex);
      if (lane == 0 && m) atomicAdd(&cnt[ex], __popcll(m));
    }
  }
  __syncthreads();
  if (tid == 0) {
    int o = 0, nmt = 0;
    for (int e = 0; e < NEXP; ++e) {
      offs[e] = o;
      int c = cnt[e];
      int nt = (c + 255) >> 8;
      for (int t = 0; t < nt; ++t) {
        tileMeta[nmt * 3 + 0] = o + t * 256;
        tileMeta[nmt * 3 + 1] = o + c;
        tileMeta[nmt * 3 + 2] = e;
        ++nmt;
      }
      o += c;
    }
    gMeta[0] = nmt;
  }
  __syncthreads();
  for (int p = tid; p < npairs; p += blockDim.x) {
    int e = sel_idx[p];
    int pos = 0;
#pragma unroll
    for (int ex = 0; ex < NEXP; ++ex) {
      unsigned long long m = __ballot(e == ex);
      if (m) {
        int leader = __ffsll((long long)m) - 1;
        int base = 0;
        if (lane == leader) base = atomicAdd(&cur[ex], __popcll(m));
        base = __shfl(base, leader, 64);
        if (e == ex)
          pos = offs[ex] + base + __popcll(m & ((1ull << lane) - 1ull));
      }
    }
    row_token[pos] = p >> 1;
    row_w[pos] = sel_w[p];
    pos_of[p] = pos;
  }
}

// ---------- gather selected token rows -> bf16
__global__ void k_gather(const float* __restrict__ x, const int* __restrict__ row_token,
                         u16* __restrict__ Xg, int npairs) {
  int pos = (blockIdx.x << 2) + (threadIdx.x >> 6);
  int lane = threadIdx.x & 63;
  if (pos >= npairs) return;
  int tok = row_token[pos];
  const float4* src = (const float4*)(x + (size_t)tok * DM);
  float4 a = src[lane * 2], b = src[lane * 2 + 1];
  uint4 o;
  o.x = pack_bf2(a.x, a.y);
  o.y = pack_bf2(a.z, a.w);
  o.z = pack_bf2(b.x, b.y);
  o.w = pack_bf2(b.z, b.w);
  ((uint4*)(Xg + (size_t)pos * DM))[lane] = o;
}

// ---------- 256x256 grouped GEMM, 512 thr / 8 waves (2Mx4N), BK=64, 2x64KB dbuf,
// tile entry: {vmcnt(0); barrier}  (per-wave drain THEN rendezvous -- R11 race fix),
// then FOUR fine phases: {8 ds_read_b128; stage half (phases 0/1); setprio;
// 16 MFMA; setprio; barrier}.  Swizzle: 128B rows, byte ^= (row&7)<<4.
// Out: bf16 [NSPLIT][npairs][NFULL] (split stride pstride u16 elems)
template <int NFULL, int KTOT, int NSPLIT, bool GELU, bool SCALE>
__launch_bounds__(512, 2)
__global__ void k_gemm256(const u16* __restrict__ A, const u16* __restrict__ BT,
                          const float* __restrict__ bias, const float* __restrict__ row_w,
                          u16* __restrict__ Out, size_t pstride,
                          const int* __restrict__ tileMeta, const int* __restrict__ gMeta,
                          int maxmt) {
  constexpr int NTN = NFULL / 256;
  constexpr int KCH = KTOT / NSPLIT;
  constexpr int NK  = KCH / 64;

  // dbuf P: A-half0 @P*64KB, A-half1 @+16KB, B-half0 @+32KB, B-half1 @+48KB
  __shared__ __align__(16) char smem[131072];

  int NB = gridDim.x;
  int bid = blockIdx.x;
  int wg = ((NB & 7) == 0) ? ((bid & 7) * (NB >> 3) + (bid >> 3)) : bid;  // XCD chunking
  int nt = wg % NTN;
  int rem = wg / NTN;
  int mt = rem % maxmt;
  int split = rem / maxmt;
  if (mt >= gMeta[0]) return;
  int posStart = tileMeta[mt * 3 + 0];
  int segEnd   = tileMeta[mt * 3 + 1];
  int e        = tileMeta[mt * 3 + 2];

  int tid = threadIdx.x, lane = tid & 63, wid = tid >> 6;
  int wm = wid >> 2, wn = wid & 3;   // 2 x 4 waves; wave tile 128 x 64

  const u16* Ab = A + (size_t)split * KCH;
  const u16* Bb = BT + ((size_t)e * NFULL + (size_t)nt * 256) * KTOT + (size_t)split * KCH;

  // staging: half = 128 rows x 128B. 512 thr x 2 instrs; thread t -> row i*64+(t>>3),
  // chunk t&7. Source pre-swizzled: chunk_src = (t&7) ^ (localrow & 7).
  int srow = tid >> 3, schunk = tid & 3 | (tid & 7);  // keep simple: schunk = tid & 7
  schunk = tid & 7;
  int skey = srow & 7;
  const u16* aP[4];                        // j = H*2 + i
  const u16* bP[4];
#pragma unroll
  for (int j = 0; j < 4; ++j) {
    int H = j >> 1, i = j & 1;
    int rl = H * 128 + i * 64 + srow;      // local-in-tile row 0..255
    int g = posStart + rl; if (g >= segEnd) g = segEnd - 1;
    aP[j] = Ab + (size_t)g * KTOT + ((schunk ^ skey) << 3);
    bP[j] = Bb + (size_t)rl * KTOT + ((schunk ^ skey) << 3);
  }

  auto stageA = [&](int t) {
    char* dst = smem + (t & 1) * 65536;
#pragma unroll
    for (int j = 0; j < 4; ++j)
      async16(aP[j] + t * 64, (u16*)(dst + (j >> 1) * 16384 + (j & 1) * 8192 + tid * 16));
  };
  auto stageB = [&](int t) {
    char* dst = smem + (t & 1) * 65536 + 32768;
#pragma unroll
    for (int j = 0; j < 4; ++j)
      async16(bP[j] + t * 64, (u16*)(dst + (j >> 1) * 16384 + (j & 1) * 8192 + tid * 16));
  };

  f32x4 acc[8][4] = {};
  int l15 = lane & 15, kg = lane >> 4;

  stageA(0); stageB(0);

#pragma unroll 1
  for (int t = 0; t < NK; ++t) {
    // ---- tile entry: every wave drains ITS OWN loads, then all rendezvous.
    asm volatile("s_waitcnt vmcnt(0)" ::: "memory");
    __builtin_amdgcn_s_barrier();
    asm volatile("" ::: "memory");
    const char* base = smem + (t & 1) * 65536;
    const char* Abase = base + wm * 16384;
    const char* Bbase = base + 32768 + (wn >> 1) * 16384;
#pragma unroll
    for (int q = 0; q < 4; ++q) {
      const int mh = q >> 1, ks = q & 1;
      bf16x8 av[4], bv[4];
#pragma unroll
      for (int mi = 0; mi < 4; ++mi) {
        int rl = (mh << 6) + (mi << 4) + l15;      // 0..127 within A-half
        av[mi] = *(const bf16x8*)(Abase + rl * 128 +
                                  ((ks * 64 + kg * 16) ^ ((rl & 7) << 4)));
      }
#pragma unroll
      for (int ni = 0; ni < 4; ++ni) {
        int rb = ((wn & 1) << 6) + (ni << 4) + l15;  // 0..127 within B-half
        bv[ni] = *(const bf16x8*)(Bbase + rb * 128 +
                                  ((ks * 64 + kg * 16) ^ ((rb & 7) << 4)));
      }
      if (q == 0 && t + 1 < NK) stageA(t + 1);
      if (q == 1 && t + 1 < NK) stageB(t + 1);
      __builtin_amdgcn_s_setprio(1);
#pragma unroll
      for (int mi = 0; mi < 4; ++mi)
#pragma unroll
        for (int ni = 0; ni < 4; ++ni)
          acc[(mh << 2) + mi][ni] = __builtin_amdgcn_mfma_f32_16x16x32_bf16(
              av[mi], bv[ni], acc[(mh << 2) + mi][ni], 0, 0, 0);
      __builtin_amdgcn_s_setprio(0);
      if (q < 3) __builtin_amdgcn_s_barrier();
    }
  }

  // ---------- epilogue (verified in R6): acc -> LDS [256 rows][512B] swizzled -> 16B stores
  __syncthreads();
  const float* biasE = bias + (size_t)e * NFULL;
  u16* OutS = Out + (size_t)split * pstride;
#pragma unroll
  for (int mi = 0; mi < 8; ++mi) {
#pragma unroll
    for (int j = 0; j < 4; ++j) {
      int r = (wm << 7) + (mi << 4) + ((lane >> 4) << 2) + j;
      int m = posStart + r;
      int mc = m < segEnd ? m : segEnd - 1;
      float w = 1.0f;
      if constexpr (SCALE) w = row_w[mc];
#pragma unroll
      for (int ni = 0; ni < 4; ++ni) {
        int c = (wn << 6) + (ni << 4) + (lane & 15);
        float v = acc[mi][ni][j];
        if (split == 0) v += biasE[nt * 256 + c];
        if constexpr (GELU) v = gelu_tanh(v);
        if constexpr (SCALE) v *= w;
        *(u16*)(smem + r * 512 + ((c * 2) ^ ((r & 7) << 4))) = f2bf(v);
      }
    }
  }
  __syncthreads();
  // 512B per row = 32 x 16B chunks; 32 threads/row, 16 rows/pass, 16 passes.
#pragma unroll
  for (int pass = 0; pass < 16; ++pass) {
    int rr = pass * 16 + (tid >> 5);
    int q  = tid & 31;
    int m = posStart + rr;
    if (m < segEnd) {
      uint4 v = *(const uint4*)(smem + rr * 512 + ((q * 16) ^ ((rr & 7) << 4)));
      *((uint4*)(OutS + (size_t)m * NFULL + nt * 256) + q) = v;
    }
  }
}

// ---------- combine: out[tok] = sum over splits x {pos0,pos1} of bf16 partials
template <int NSPLIT>
__global__ void k_combine(const u16* __restrict__ P, size_t pstride,
                          const int* __restrict__ pos_of, float* __restrict__ out, int Ntok) {
  int tok = (blockIdx.x << 2) + (threadIdx.x >> 6);
  int lane = threadIdx.x & 63;
  if (tok >= Ntok) return;
  int p0 = pos_of[tok * 2], p1 = pos_of[tok * 2 + 1];
  float s[8] = {};
#pragma unroll
  for (int sp = 0; sp < NSPLIT; ++sp) {
    bf16x8 a = ((const bf16x8*)(P + sp * pstride + (size_t)p0 * DM))[lane];
    bf16x8 b = ((const bf16x8*)(P + sp * pstride + (size_t)p1 * DM))[lane];
#pragma unroll
    for (int i = 0; i < 8; ++i) s[i] += (float)a[i] + (float)b[i];
  }
  float4* o = (float4*)(out + (size_t)tok * DM + lane * 8);
  o[0] = make_float4(s[0], s[1], s[2], s[3]);
  o[1] = make_float4(s[4], s[5], s[6], s[7]);
}

extern "C" void kernel_launch(void* const* d_in, const int* in_sizes, int n_in,
                              void* d_out, int out_size, void* d_ws, size_t ws_size,
                              hipStream_t stream) {
  const float* x  = (const float*)d_in[0];
  const float* Wr = (const float*)d_in[1];
  const float* br = (const float*)d_in[2];
  const float* W1 = (const float*)d_in[3];
  const float* b1 = (const float*)d_in[4];
  const float* W2 = (const float*)d_in[5];
  const float* b2 = (const float*)d_in[6];
  float* out = (float*)d_out;

  int Ntok = in_sizes[0] / DM;          // 4096
  int npairs = Ntok * 2;                // 8192
  int maxmt = npairs / 256 + NEXP;      // 40
  size_t pstride = (size_t)npairs * DM; // u16 elems per split

  char* p = (char*)d_ws;
  u16* W1T = (u16*)p;  p += (size_t)NEXP * DFF * DM * 2;
  u16* W2T = (u16*)p;  p += (size_t)NEXP * DM * DFF * 2;
  u16* Xg  = (u16*)p;  p += (size_t)npairs * DM * 2;
  u16* H   = (u16*)p;  p += (size_t)npairs * DFF * 2;
  u16* Part = (u16*)p; p += 4 * pstride * 2;          // [4][npairs][DM] bf16
  int* sel_idx   = (int*)p;   p += (size_t)npairs * 4;
  float* sel_w   = (float*)p; p += (size_t)npairs * 4;
  int* pos_of    = (int*)p;   p += (size_t)npairs * 4;
  int* row_token = (int*)p;   p += (size_t)npairs * 4;
  float* row_w   = (float*)p; p += (size_t)npairs * 4;
  int* tileMeta  = (int*)p;   p += (size_t)(maxmt * 3 + 16) * 4;
  int* gMeta     = (int*)p;   p += 64;

  k_prep<<<dim3(4096 + Ntok / 4), 256, 0, stream>>>(W1, W1T, W2, W2T, x, Wr, br,
                                                    sel_idx, sel_w, Ntok);
  k_scatter<<<dim3(1), 1024, 0, stream>>>(sel_idx, sel_w, npairs, row_token, row_w,
                                          pos_of, tileMeta, gMeta);
  k_gather<<<dim3(npairs / 4), 256, 0, stream>>>(x, row_token, Xg, npairs);
  // GEMM1: H = gelu(Xg * W1T + b1), 256x256, grid 40*8 = 320
  k_gemm256<DFF, DM, 1, true, false>
      <<<dim3(maxmt * (DFF / 256)), 512, 0, stream>>>(
          Xg, W1T, b1, nullptr, H, 0, tileMeta, gMeta, maxmt);
  // GEMM2: Part[s] = (H_s * W2T_s + (s==0)*b2) * row_w, split-K=4, grid 40*2*4 = 320
  k_gemm256<DM, DFF, 4, false, true>
      <<<dim3(maxmt * (DM / 256) * 4), 512, 0, stream>>>(
          H, W2T, b2, row_w, Part, pstride, tileMeta, gMeta, maxmt);
  k_combine<4><<<dim3(Ntok / 4), 256, 0, stream>>>(Part, pstride, pos_of, out, Ntok);
}

// Round 13
// 140.264 us; speedup vs baseline: 1.3029x; 1.3029x over previous
//
#include <hip/hip_runtime.h>
#include <hip/hip_bf16.h>
#include <cstdint>

typedef unsigned short u16;
typedef __bf16 bf16_t;
typedef __bf16 bf16x8 __attribute__((ext_vector_type(8)));
typedef float f32x4 __attribute__((ext_vector_type(4)));

#define DM   512
#define DFF  2048
#define NEXP 8

__device__ __forceinline__ u16 f2bf(float f) {
  bf16_t b = (bf16_t)f;
  return __builtin_bit_cast(u16, b);
}
__device__ __forceinline__ uint32_t pack_bf2(float lo, float hi) {
  return (uint32_t)f2bf(lo) | ((uint32_t)f2bf(hi) << 16);
}
__device__ __forceinline__ float gelu_tanh(float x) {
  float x3 = x * x * x;
  float z = 0.7978845608028654f * (x + 0.044715f * x3);
  float az = fabsf(z);
  float e = __expf(2.0f * az);
  float t = 1.0f - 2.0f / (e + 1.0f);
  t = copysignf(t, z);
  return 0.5f * x * (1.0f + t);
}
__device__ __forceinline__ void async16(const u16* g, u16* l) {
  __builtin_amdgcn_global_load_lds((const __attribute__((address_space(1))) void*)g,
                                   (__attribute__((address_space(3))) void*)l, 16, 0, 0);
}

// ---------- transpose tile body: src [R][C] f32 -> dst [C][R] bf16
__device__ __forceinline__ void transpose_tile(const float* __restrict__ s,
                                               u16* __restrict__ d, int R, int C,
                                               int tileIdx) {
  __shared__ u16 tile[64][66];
  int tilesC = C >> 6;
  int bR = (tileIdx / tilesC) << 6;
  int bC = (tileIdx % tilesC) << 6;
  int rr = threadIdx.x >> 4;
  int cc = (threadIdx.x & 15) << 2;
#pragma unroll
  for (int i = 0; i < 4; ++i) {
    int r = (i << 4) + rr;
    float4 v = *(const float4*)(s + (size_t)(bR + r) * C + bC + cc);
    *(uint32_t*)&tile[r][cc]     = pack_bf2(v.x, v.y);
    *(uint32_t*)&tile[r][cc + 2] = pack_bf2(v.z, v.w);
  }
  __syncthreads();
  int c0 = threadIdx.x >> 5;
  int j  = (threadIdx.x & 31) << 1;
#pragma unroll
  for (int i = 0; i < 8; ++i) {
    int c = (i << 3) + c0;
    uint32_t v = (uint32_t)tile[j][c] | ((uint32_t)tile[j + 1][c] << 16);
    *(uint32_t*)(&d[(size_t)(bC + c) * R + bR + j]) = v;
  }
}

// ---------- fused prep: W1 transpose | W2 transpose | x->bf16 | router
__global__ void k_prep(const float* __restrict__ W1, u16* __restrict__ W1T,
                       const float* __restrict__ W2, u16* __restrict__ W2T,
                       const float* __restrict__ x, u16* __restrict__ Xb,
                       const float* __restrict__ Wr, const float* __restrict__ br,
                       int* __restrict__ sel_idx, float* __restrict__ sel_w, int Ntok) {
  int b = blockIdx.x;
  if (b < 2048) {
    int e = b >> 8, t = b & 255;
    transpose_tile(W1 + (size_t)e * DM * DFF, W1T + (size_t)e * DM * DFF, DM, DFF, t);
    return;
  }
  if (b < 4096) {
    int e = (b - 2048) >> 8, t = (b - 2048) & 255;
    transpose_tile(W2 + (size_t)e * DFF * DM, W2T + (size_t)e * DFF * DM, DFF, DM, t);
    return;
  }
  if (b < 5120) {
    // x -> bf16 copy: block handles 2048 f32, thread handles 8
    size_t base = ((size_t)(b - 4096) << 11) + ((size_t)threadIdx.x << 3);
    float4 a = *(const float4*)(x + base);
    float4 c = *(const float4*)(x + base + 4);
    uint4 o;
    o.x = pack_bf2(a.x, a.y);
    o.y = pack_bf2(a.z, a.w);
    o.z = pack_bf2(c.x, c.y);
    o.w = pack_bf2(c.z, c.w);
    *(uint4*)(Xb + base) = o;
    return;
  }
  int rb = b - 5120;
  int wid = threadIdx.x >> 6;
  int lane = threadIdx.x & 63;
  int tok = (rb << 2) + wid;
  if (tok >= Ntok) return;
  const float4* xr = (const float4*)(x + (size_t)tok * DM);
  float4 x0 = xr[lane * 2], x1 = xr[lane * 2 + 1];
  float logit[NEXP];
#pragma unroll
  for (int e = 0; e < NEXP; ++e) {
    const float4* wr = (const float4*)(Wr + e * DM);
    float4 w0 = wr[lane * 2], w1 = wr[lane * 2 + 1];
    float p = x0.x * w0.x + x0.y * w0.y + x0.z * w0.z + x0.w * w0.w
            + x1.x * w1.x + x1.y * w1.y + x1.z * w1.z + x1.w * w1.w;
#pragma unroll
    for (int off = 32; off; off >>= 1) p += __shfl_xor(p, off, 64);
    logit[e] = p + br[e];
  }
  if (lane == 0) {
    float mx = logit[0];
#pragma unroll
    for (int e = 1; e < NEXP; ++e) mx = fmaxf(mx, logit[e]);
    float pr[NEXP];
#pragma unroll
    for (int e = 0; e < NEXP; ++e) pr[e] = __expf(logit[e] - mx);
    int i0 = 0;
#pragma unroll
    for (int e = 1; e < NEXP; ++e) if (pr[e] > pr[i0]) i0 = e;
    int i1 = -1;
#pragma unroll
    for (int e = 0; e < NEXP; ++e) {
      if (e == i0) continue;
      if (i1 < 0 || pr[e] > pr[i1]) i1 = e;
    }
    float s2 = pr[i0] + pr[i1];
    sel_idx[tok * 2]     = i0;
    sel_idx[tok * 2 + 1] = i1;
    sel_w[tok * 2]       = pr[i0] / s2;
    sel_w[tok * 2 + 1]   = pr[i1] / s2;
  }
}

// ---------- scatter (1 block, ballot-based), 128-row tile granularity
__global__ void k_scatter(const int* __restrict__ sel_idx, const float* __restrict__ sel_w,
                          int npairs, int* __restrict__ row_token, float* __restrict__ row_w,
                          int* __restrict__ pos_of, int* __restrict__ tileMeta,
                          int* __restrict__ gMeta) {
  __shared__ int cnt[NEXP], offs[NEXP], cur[NEXP];
  int tid = threadIdx.x;
  int lane = tid & 63;
  if (tid < NEXP) { cnt[tid] = 0; cur[tid] = 0; }
  __syncthreads();
  for (int p = tid; p < npairs; p += blockDim.x) {
    int e = sel_idx[p];
#pragma unroll
    for (int ex = 0; ex < NEXP; ++ex) {
      unsigned long long m = __ballot(e == ex);
      if (lane == 0 && m) atomicAdd(&cnt[ex], __popcll(m));
    }
  }
  __syncthreads();
  if (tid == 0) {
    int o = 0, nmt = 0;
    for (int e = 0; e < NEXP; ++e) {
      offs[e] = o;
      int c = cnt[e];
      int nt = (c + 127) >> 7;
      for (int t = 0; t < nt; ++t) {
        tileMeta[nmt * 3 + 0] = o + t * 128;
        tileMeta[nmt * 3 + 1] = o + c;
        tileMeta[nmt * 3 + 2] = e;
        ++nmt;
      }
      o += c;
    }
    gMeta[0] = nmt;
  }
  __syncthreads();
  for (int p = tid; p < npairs; p += blockDim.x) {
    int e = sel_idx[p];
    int pos = 0;
#pragma unroll
    for (int ex = 0; ex < NEXP; ++ex) {
      unsigned long long m = __ballot(e == ex);
      if (m) {
        int leader = __ffsll((long long)m) - 1;
        int base = 0;
        if (lane == leader) base = atomicAdd(&cur[ex], __popcll(m));
        base = __shfl(base, leader, 64);
        if (e == ex)
          pos = offs[ex] + base + __popcll(m & ((1ull << lane) - 1ull));
      }
    }
    row_token[pos] = p >> 1;
    row_w[pos] = sel_w[p];
    pos_of[p] = pos;
  }
}

// ---------- grouped GEMM (R3-proven core): 128x128, BK=32, 3-slot ring,
// counted vmcnt(4), 1 barrier/K-tile, 256 thr / 4 waves (2x2), 48KB -> 3 blocks/CU.
// rowMap (optional): A-row indirection (GEMM1 reads token rows of Xb directly).
// OUTBF16: Out = bf16 [.][NFULL] (GELU).  else: f32 partial at split*pstride (SCALE).
template <int NFULL, int KTOT, int KCHUNK, bool GELU, bool SCALE, bool OUTBF16, bool USEMAP>
__launch_bounds__(256)
__global__ void k_gemm(const u16* __restrict__ A, const int* __restrict__ rowMap,
                       const u16* __restrict__ BT,
                       const float* __restrict__ bias, const float* __restrict__ row_w,
                       void* __restrict__ Out, size_t pstride,
                       const int* __restrict__ tileMeta, const int* __restrict__ gMeta,
                       int maxmt) {
  constexpr int NT = NFULL / 128;
  constexpr int NK = KCHUNK / 32;
  int NB = gridDim.x;
  int bid = blockIdx.x;
  int wg = ((NB & 7) == 0) ? ((bid & 7) * (NB >> 3) + (bid >> 3)) : bid;  // XCD chunking
  int nt = wg % NT;                      // nt fastest -> A-tile L2 reuse within XCD
  int rem = wg / NT;
  int mt = rem % maxmt;
  int split = rem / maxmt;
  if (mt >= gMeta[0]) return;
  int posStart = tileMeta[mt * 3 + 0];
  int segEnd   = tileMeta[mt * 3 + 1];
  int e        = tileMeta[mt * 3 + 2];

  // 3 buffers x (A 128x32 + B 128x32) u16 = 3 x 16KB = 48KB
  __shared__ __align__(16) u16 smem[24576];

  int tid = threadIdx.x, lane = tid & 63, wid = tid >> 6;
  int wm = wid >> 1, wn = wid & 1;

  const u16* Abase = A + (size_t)split * KCHUNK;
  const u16* Bbase = BT + ((size_t)e * NFULL + (size_t)nt * 128) * KTOT + (size_t)split * KCHUNK;

  // staging: wave w instr i covers tile rows [i*64 + w*16, +16), 64B/row, linear LDS dest.
  // global source pre-swizzled: chunk cs = c4 ^ ((row>>1)&3)  (2-way max on read = free)
  int l4 = lane >> 2, c4 = lane & 3;
  const u16* aS[2];
  const u16* bS[2];
#pragma unroll
  for (int i = 0; i < 2; ++i) {
    int r = i * 64 + wid * 16 + l4;
    int gra = posStart + r;
    if (gra >= segEnd) gra = segEnd - 1;
    if constexpr (USEMAP) gra = rowMap[gra];
    int cs = c4 ^ ((r >> 1) & 3);
    aS[i] = Abase + (size_t)gra * KTOT + cs * 8;
    bS[i] = Bbase + (size_t)r * KTOT + cs * 8;
  }

  auto stage = [&](int kt, int buf) {
    u16* as = smem + buf * 8192;
    u16* bs = as + 4096;
#pragma unroll
    for (int i = 0; i < 2; ++i) {
      async16(aS[i] + kt * 32, as + i * 2048 + wid * 512);
      async16(bS[i] + kt * 32, bs + i * 2048 + wid * 512);
    }
  };

  f32x4 acc[4][4] = {};

  stage(0, 0);
  stage(1, 1);
  int bufC = 0, bufS = 2;
#pragma unroll 1
  for (int t = 0; t < NK; ++t) {
    if (t + 1 < NK) asm volatile("s_waitcnt vmcnt(4)" ::: "memory");
    else            asm volatile("s_waitcnt vmcnt(0)" ::: "memory");
    __builtin_amdgcn_s_barrier();
    asm volatile("" ::: "memory");
    if (t + 2 < NK) { stage(t + 2, bufS); bufS = (bufS == 2) ? 0 : bufS + 1; }
    const char* AsB = (const char*)(smem + bufC * 8192);
    const char* BsB = AsB + 8192;
    int kb = (lane >> 4) << 4;
    bf16x8 av[4], bv[4];
#pragma unroll
    for (int mi = 0; mi < 4; ++mi) {
      int row = (wm << 6) + (mi << 4) + (lane & 15);
      av[mi] = *(const bf16x8*)(AsB + row * 64 + (kb ^ (((row >> 1) & 3) << 4)));
    }
#pragma unroll
    for (int ni = 0; ni < 4; ++ni) {
      int row = (wn << 6) + (ni << 4) + (lane & 15);
      bv[ni] = *(const bf16x8*)(BsB + row * 64 + (kb ^ (((row >> 1) & 3) << 4)));
    }
    __builtin_amdgcn_s_setprio(1);
#pragma unroll
    for (int mi = 0; mi < 4; ++mi)
#pragma unroll
      for (int ni = 0; ni < 4; ++ni)
        acc[mi][ni] = __builtin_amdgcn_mfma_f32_16x16x32_bf16(av[mi], bv[ni], acc[mi][ni], 0, 0, 0);
    __builtin_amdgcn_s_setprio(0);
    bufC = (bufC == 2) ? 0 : bufC + 1;
  }

  int laneCol = lane & 15;
  int laneRow4 = (lane >> 4) << 2;
  const float* biasE = bias + (size_t)e * NFULL;

  if constexpr (OUTBF16) {
    __syncthreads();
    u16* Cs = smem;   // 128 x 136 u16 = 34KB (16B-aligned rows)
#pragma unroll
    for (int mi = 0; mi < 4; ++mi) {
#pragma unroll
      for (int j = 0; j < 4; ++j) {
        int r = (wm << 6) + (mi << 4) + laneRow4 + j;
#pragma unroll
        for (int ni = 0; ni < 4; ++ni) {
          int cl = (wn << 6) + (ni << 4) + laneCol;
          float v = acc[mi][ni][j] + biasE[(nt << 7) + cl];
          if constexpr (GELU) v = gelu_tanh(v);
          Cs[r * 136 + cl] = f2bf(v);
        }
      }
    }
    __syncthreads();
    int r0 = tid >> 4, q = tid & 15;
    u16* OutU = (u16*)Out;
#pragma unroll
    for (int i = 0; i < 8; ++i) {
      int r = (i << 4) + r0;
      if (posStart + r < segEnd)
        *((uint4*)(OutU + (size_t)(posStart + r) * NFULL + (nt << 7)) + q) =
            ((uint4*)(Cs + (size_t)r * 136))[q];
    }
  } else {
    float* OutF = (float*)Out + (size_t)split * pstride;
#pragma unroll
    for (int mi = 0; mi < 4; ++mi) {
#pragma unroll
      for (int j = 0; j < 4; ++j) {
        int m = posStart + (wm << 6) + (mi << 4) + laneRow4 + j;
        if (m < segEnd) {
          float w = 1.0f;
          if constexpr (SCALE) w = row_w[m];
#pragma unroll
          for (int ni = 0; ni < 4; ++ni) {
            int n = (nt << 7) + (wn << 6) + (ni << 4) + laneCol;
            float v = acc[mi][ni][j] + (split == 0 ? biasE[n] : 0.0f);
            OutF[(size_t)m * NFULL + n] = v * w;
          }
        }
      }
    }
  }
}

// ---------- combine: out[tok] = sum over {split0,split1} x {pos0,pos1} of f32 partials
__global__ void k_combine(const float* __restrict__ P, size_t pstride,
                          const int* __restrict__ pos_of, float* __restrict__ out, int Ntok) {
  int tok = (blockIdx.x << 2) + (threadIdx.x >> 6);
  int lane = threadIdx.x & 63;
  if (tok >= Ntok) return;
  int p0 = pos_of[tok * 2], p1 = pos_of[tok * 2 + 1];
  const float4* a0 = (const float4*)(P + (size_t)p0 * DM);
  const float4* a1 = (const float4*)(P + pstride + (size_t)p0 * DM);
  const float4* b0 = (const float4*)(P + (size_t)p1 * DM);
  const float4* b1 = (const float4*)(P + pstride + (size_t)p1 * DM);
  float4* o = (float4*)(out + (size_t)tok * DM);
#pragma unroll
  for (int i = 0; i < 2; ++i) {
    int idx = lane * 2 + i;
    float4 x0 = a0[idx], x1 = a1[idx], y0 = b0[idx], y1 = b1[idx];
    o[idx] = make_float4(x0.x + x1.x + y0.x + y1.x,
                         x0.y + x1.y + y0.y + y1.y,
                         x0.z + x1.z + y0.z + y1.z,
                         x0.w + x1.w + y0.w + y1.w);
  }
}

extern "C" void kernel_launch(void* const* d_in, const int* in_sizes, int n_in,
                              void* d_out, int out_size, void* d_ws, size_t ws_size,
                              hipStream_t stream) {
  const float* x  = (const float*)d_in[0];
  const float* Wr = (const float*)d_in[1];
  const float* br = (const float*)d_in[2];
  const float* W1 = (const float*)d_in[3];
  const float* b1 = (const float*)d_in[4];
  const float* W2 = (const float*)d_in[5];
  const float* b2 = (const float*)d_in[6];
  float* out = (float*)d_out;

  int Ntok = in_sizes[0] / DM;          // 4096
  int npairs = Ntok * 2;                // 8192
  int maxmt = npairs / 128 + NEXP;      // 72
  size_t pstride = (size_t)npairs * DM; // f32 elems per split

  char* p = (char*)d_ws;
  u16* W1T = (u16*)p;  p += (size_t)NEXP * DFF * DM * 2;
  u16* W2T = (u16*)p;  p += (size_t)NEXP * DM * DFF * 2;
  u16* Xb  = (u16*)p;  p += (size_t)Ntok * DM * 2;
  u16* H   = (u16*)p;  p += (size_t)npairs * DFF * 2;
  float* Part = (float*)p; p += 2 * pstride * 4;   // [2][npairs][DM] f32
  int* sel_idx   = (int*)p;   p += (size_t)npairs * 4;
  float* sel_w   = (float*)p; p += (size_t)npairs * 4;
  int* pos_of    = (int*)p;   p += (size_t)npairs * 4;
  int* row_token = (int*)p;   p += (size_t)npairs * 4;
  float* row_w   = (float*)p; p += (size_t)npairs * 4;
  int* tileMeta  = (int*)p;   p += (size_t)(maxmt * 3 + 16) * 4;
  int* gMeta     = (int*)p;   p += 64;

  // prep: 2048 (W1T) + 2048 (W2T) + 1024 (x->bf16) + Ntok/4 (router)
  k_prep<<<dim3(5120 + Ntok / 4), 256, 0, stream>>>(W1, W1T, W2, W2T, x, Xb, Wr, br,
                                                    sel_idx, sel_w, Ntok);
  k_scatter<<<dim3(1), 1024, 0, stream>>>(sel_idx, sel_w, npairs, row_token, row_w,
                                          pos_of, tileMeta, gMeta);
  // GEMM1: H[pos][2048] = gelu(Xb[row_token[pos]] * W1T + b1)  (A via rowMap)
  k_gemm<DFF, DM, DM, true, false, true, true>
      <<<dim3(maxmt * (DFF / 128)), 256, 0, stream>>>(
          Xb, row_token, W1T, b1, nullptr, H, 0, tileMeta, gMeta, maxmt);
  // GEMM2: split-K=2, f32 partials, bias on split0, row_w scale
  k_gemm<DM, DFF, DFF / 2, false, true, false, false>
      <<<dim3(maxmt * (DM / 128) * 2), 256, 0, stream>>>(
          H, nullptr, W2T, b2, row_w, Part, pstride, tileMeta, gMeta, maxmt);
  k_combine<<<dim3(Ntok / 4), 256, 0, stream>>>(Part, pstride, pos_of, out, Ntok);
}

// Round 14
// 132.697 us; speedup vs baseline: 1.3772x; 1.0570x over previous
//
#include <hip/hip_runtime.h>
#include <hip/hip_bf16.h>
#include <cstdint>

typedef unsigned short u16;
typedef __bf16 bf16_t;
typedef __bf16 bf16x8 __attribute__((ext_vector_type(8)));
typedef float f32x4 __attribute__((ext_vector_type(4)));

#define DM   512
#define DFF  2048
#define NEXP 8

__device__ __forceinline__ u16 f2bf(float f) {
  bf16_t b = (bf16_t)f;
  return __builtin_bit_cast(u16, b);
}
__device__ __forceinline__ uint32_t pack_bf2(float lo, float hi) {
  return (uint32_t)f2bf(lo) | ((uint32_t)f2bf(hi) << 16);
}
__device__ __forceinline__ float gelu_tanh(float x) {
  float x3 = x * x * x;
  float z = 0.7978845608028654f * (x + 0.044715f * x3);
  float az = fabsf(z);
  float e = __expf(2.0f * az);
  float t = 1.0f - 2.0f / (e + 1.0f);
  t = copysignf(t, z);
  return 0.5f * x * (1.0f + t);
}
__device__ __forceinline__ void async16(const u16* g, u16* l) {
  __builtin_amdgcn_global_load_lds((const __attribute__((address_space(1))) void*)g,
                                   (__attribute__((address_space(3))) void*)l, 16, 0, 0);
}

// ---------- transpose tile body: src [R][C] f32 -> dst [C][R] bf16 (16B stores)
__device__ __forceinline__ void transpose_tile(const float* __restrict__ s,
                                               u16* __restrict__ d, int R, int C,
                                               int tileIdx) {
  __shared__ u16 tile[64][66];
  int tilesC = C >> 6;
  int bR = (tileIdx / tilesC) << 6;
  int bC = (tileIdx % tilesC) << 6;
  int rr = threadIdx.x >> 4;
  int cc = (threadIdx.x & 15) << 2;
#pragma unroll
  for (int i = 0; i < 4; ++i) {
    int r = (i << 4) + rr;
    float4 v = *(const float4*)(s + (size_t)(bR + r) * C + bC + cc);
    *(uint32_t*)&tile[r][cc]     = pack_bf2(v.x, v.y);
    *(uint32_t*)&tile[r][cc + 2] = pack_bf2(v.z, v.w);
  }
  __syncthreads();
  int c  = threadIdx.x >> 3;          // 0..31
  int j0 = (threadIdx.x & 7) << 3;    // 0,8,...,56
#pragma unroll
  for (int half = 0; half < 2; ++half) {
    int cc2 = c + (half << 5);
    uint32_t w0 = (uint32_t)tile[j0 + 0][cc2] | ((uint32_t)tile[j0 + 1][cc2] << 16);
    uint32_t w1 = (uint32_t)tile[j0 + 2][cc2] | ((uint32_t)tile[j0 + 3][cc2] << 16);
    uint32_t w2 = (uint32_t)tile[j0 + 4][cc2] | ((uint32_t)tile[j0 + 5][cc2] << 16);
    uint32_t w3 = (uint32_t)tile[j0 + 6][cc2] | ((uint32_t)tile[j0 + 7][cc2] << 16);
    *(uint4*)(&d[(size_t)(bC + cc2) * R + bR + j0]) = make_uint4(w0, w1, w2, w3);
  }
}

// ---------- fused prep: W1 transpose | W2 transpose | x->bf16 | router
__global__ void k_prep(const float* __restrict__ W1, u16* __restrict__ W1T,
                       const float* __restrict__ W2, u16* __restrict__ W2T,
                       const float* __restrict__ x, u16* __restrict__ Xb,
                       const float* __restrict__ Wr, const float* __restrict__ br,
                       int* __restrict__ sel_idx, float* __restrict__ sel_w, int Ntok) {
  int b = blockIdx.x;
  if (b < 2048) {
    int e = b >> 8, t = b & 255;
    transpose_tile(W1 + (size_t)e * DM * DFF, W1T + (size_t)e * DM * DFF, DM, DFF, t);
    return;
  }
  if (b < 4096) {
    int e = (b - 2048) >> 8, t = (b - 2048) & 255;
    transpose_tile(W2 + (size_t)e * DFF * DM, W2T + (size_t)e * DFF * DM, DFF, DM, t);
    return;
  }
  if (b < 5120) {
    size_t base = ((size_t)(b - 4096) << 11) + ((size_t)threadIdx.x << 3);
    float4 a = *(const float4*)(x + base);
    float4 c = *(const float4*)(x + base + 4);
    uint4 o;
    o.x = pack_bf2(a.x, a.y);
    o.y = pack_bf2(a.z, a.w);
    o.z = pack_bf2(c.x, c.y);
    o.w = pack_bf2(c.z, c.w);
    *(uint4*)(Xb + base) = o;
    return;
  }
  int rb = b - 5120;
  int wid = threadIdx.x >> 6;
  int lane = threadIdx.x & 63;
  int tok = (rb << 2) + wid;
  if (tok >= Ntok) return;
  const float4* xr = (const float4*)(x + (size_t)tok * DM);
  float4 x0 = xr[lane * 2], x1 = xr[lane * 2 + 1];
  float logit[NEXP];
#pragma unroll
  for (int e = 0; e < NEXP; ++e) {
    const float4* wr = (const float4*)(Wr + e * DM);
    float4 w0 = wr[lane * 2], w1 = wr[lane * 2 + 1];
    float p = x0.x * w0.x + x0.y * w0.y + x0.z * w0.z + x0.w * w0.w
            + x1.x * w1.x + x1.y * w1.y + x1.z * w1.z + x1.w * w1.w;
#pragma unroll
    for (int off = 32; off; off >>= 1) p += __shfl_xor(p, off, 64);
    logit[e] = p + br[e];
  }
  if (lane == 0) {
    float mx = logit[0];
#pragma unroll
    for (int e = 1; e < NEXP; ++e) mx = fmaxf(mx, logit[e]);
    float pr[NEXP];
#pragma unroll
    for (int e = 0; e < NEXP; ++e) pr[e] = __expf(logit[e] - mx);
    int i0 = 0;
#pragma unroll
    for (int e = 1; e < NEXP; ++e) if (pr[e] > pr[i0]) i0 = e;
    int i1 = -1;
#pragma unroll
    for (int e = 0; e < NEXP; ++e) {
      if (e == i0) continue;
      if (i1 < 0 || pr[e] > pr[i1]) i1 = e;
    }
    float s2 = pr[i0] + pr[i1];
    sel_idx[tok * 2]     = i0;
    sel_idx[tok * 2 + 1] = i1;
    sel_w[tok * 2]       = pr[i0] / s2;
    sel_w[tok * 2 + 1]   = pr[i1] / s2;
  }
}

// ---------- scatter: 8 blocks, one expert each; block 0 also writes tileMeta.
// All blocks redundantly compute counts; block e assigns positions for expert e.
__global__ void k_scatter(const int* __restrict__ sel_idx, const float* __restrict__ sel_w,
                          int npairs, int* __restrict__ row_token, float* __restrict__ row_w,
                          int* __restrict__ pos_of, int* __restrict__ tileMeta,
                          int* __restrict__ gMeta) {
  __shared__ int cnt[NEXP], offs[NEXP], cur;
  int eb = blockIdx.x;          // expert this block assigns
  int tid = threadIdx.x;
  int lane = tid & 63;
  if (tid < NEXP) cnt[tid] = 0;
  if (tid == 0) cur = 0;
  __syncthreads();
  for (int p = tid; p < npairs; p += blockDim.x) {
    int e = sel_idx[p];
#pragma unroll
    for (int ex = 0; ex < NEXP; ++ex) {
      unsigned long long m = __ballot(e == ex);
      if (lane == 0 && m) atomicAdd(&cnt[ex], __popcll(m));
    }
  }
  __syncthreads();
  if (tid == 0) {
    int o = 0;
    for (int e = 0; e < NEXP; ++e) { offs[e] = o; o += cnt[e]; }
    if (eb == 0) {
      int nmt = 0;
      for (int e = 0; e < NEXP; ++e) {
        int c = cnt[e];
        int nt = (c + 127) >> 7;
        for (int t = 0; t < nt; ++t) {
          tileMeta[nmt * 3 + 0] = offs[e] + t * 128;
          tileMeta[nmt * 3 + 1] = offs[e] + c;
          tileMeta[nmt * 3 + 2] = e;
          ++nmt;
        }
      }
      gMeta[0] = nmt;
    }
  }
  __syncthreads();
  for (int p = tid; p < npairs; p += blockDim.x) {
    int e = sel_idx[p];
    unsigned long long m = __ballot(e == eb);
    if (m) {
      int leader = __ffsll((long long)m) - 1;
      int base = 0;
      if (lane == leader) base = atomicAdd(&cur, __popcll(m));
      base = __shfl(base, leader, 64);
      if (e == eb) {
        int pos = offs[eb] + base + __popcll(m & ((1ull << lane) - 1ull));
        row_token[pos] = p >> 1;
        row_w[pos] = sel_w[p];
        pos_of[p] = pos;
      }
    }
  }
}

// ---------- grouped GEMM (R3-proven core): 128x128, BK=32, 3-slot ring,
// counted vmcnt(4), 1 barrier/K-tile, 256 thr / 4 waves (2x2), 48KB -> 3 blocks/CU.
// rowMap (optional): A-row indirection. OUTBF16: bf16 out via LDS-staged 16B stores
// (supports split/pstride/SCALE/bias-on-split0).  else: f32 partial stores.
template <int NFULL, int KTOT, int KCHUNK, bool GELU, bool SCALE, bool OUTBF16, bool USEMAP>
__launch_bounds__(256)
__global__ void k_gemm(const u16* __restrict__ A, const int* __restrict__ rowMap,
                       const u16* __restrict__ BT,
                       const float* __restrict__ bias, const float* __restrict__ row_w,
                       void* __restrict__ Out, size_t pstride,
                       const int* __restrict__ tileMeta, const int* __restrict__ gMeta,
                       int maxmt) {
  constexpr int NT = NFULL / 128;
  constexpr int NK = KCHUNK / 32;
  int NB = gridDim.x;
  int bid = blockIdx.x;
  int wg = ((NB & 7) == 0) ? ((bid & 7) * (NB >> 3) + (bid >> 3)) : bid;  // XCD chunking
  int nt = wg % NT;                      // nt fastest -> A-tile L2 reuse within XCD
  int rem = wg / NT;
  int mt = rem % maxmt;
  int split = rem / maxmt;
  if (mt >= gMeta[0]) return;
  int posStart = tileMeta[mt * 3 + 0];
  int segEnd   = tileMeta[mt * 3 + 1];
  int e        = tileMeta[mt * 3 + 2];

  __shared__ __align__(16) u16 smem[24576];

  int tid = threadIdx.x, lane = tid & 63, wid = tid >> 6;
  int wm = wid >> 1, wn = wid & 1;

  const u16* Abase = A + (size_t)split * KCHUNK;
  const u16* Bbase = BT + ((size_t)e * NFULL + (size_t)nt * 128) * KTOT + (size_t)split * KCHUNK;

  int l4 = lane >> 2, c4 = lane & 3;
  const u16* aS[2];
  const u16* bS[2];
#pragma unroll
  for (int i = 0; i < 2; ++i) {
    int r = i * 64 + wid * 16 + l4;
    int gra = posStart + r;
    if (gra >= segEnd) gra = segEnd - 1;
    if constexpr (USEMAP) gra = rowMap[gra];
    int cs = c4 ^ ((r >> 1) & 3);
    aS[i] = Abase + (size_t)gra * KTOT + cs * 8;
    bS[i] = Bbase + (size_t)r * KTOT + cs * 8;
  }

  auto stage = [&](int kt, int buf) {
    u16* as = smem + buf * 8192;
    u16* bs = as + 4096;
#pragma unroll
    for (int i = 0; i < 2; ++i) {
      async16(aS[i] + kt * 32, as + i * 2048 + wid * 512);
      async16(bS[i] + kt * 32, bs + i * 2048 + wid * 512);
    }
  };

  f32x4 acc[4][4] = {};

  stage(0, 0);
  stage(1, 1);
  int bufC = 0, bufS = 2;
#pragma unroll 1
  for (int t = 0; t < NK; ++t) {
    if (t + 1 < NK) asm volatile("s_waitcnt vmcnt(4)" ::: "memory");
    else            asm volatile("s_waitcnt vmcnt(0)" ::: "memory");
    __builtin_amdgcn_s_barrier();
    asm volatile("" ::: "memory");
    if (t + 2 < NK) { stage(t + 2, bufS); bufS = (bufS == 2) ? 0 : bufS + 1; }
    const char* AsB = (const char*)(smem + bufC * 8192);
    const char* BsB = AsB + 8192;
    int kb = (lane >> 4) << 4;
    bf16x8 av[4], bv[4];
#pragma unroll
    for (int mi = 0; mi < 4; ++mi) {
      int row = (wm << 6) + (mi << 4) + (lane & 15);
      av[mi] = *(const bf16x8*)(AsB + row * 64 + (kb ^ (((row >> 1) & 3) << 4)));
    }
#pragma unroll
    for (int ni = 0; ni < 4; ++ni) {
      int row = (wn << 6) + (ni << 4) + (lane & 15);
      bv[ni] = *(const bf16x8*)(BsB + row * 64 + (kb ^ (((row >> 1) & 3) << 4)));
    }
    __builtin_amdgcn_s_setprio(1);
#pragma unroll
    for (int mi = 0; mi < 4; ++mi)
#pragma unroll
      for (int ni = 0; ni < 4; ++ni)
        acc[mi][ni] = __builtin_amdgcn_mfma_f32_16x16x32_bf16(av[mi], bv[ni], acc[mi][ni], 0, 0, 0);
    __builtin_amdgcn_s_setprio(0);
    bufC = (bufC == 2) ? 0 : bufC + 1;
  }

  int laneCol = lane & 15;
  int laneRow4 = (lane >> 4) << 2;
  const float* biasE = bias + (size_t)e * NFULL;

  if constexpr (OUTBF16) {
    __syncthreads();
    u16* Cs = smem;   // 128 x 136 u16 = 34KB
#pragma unroll
    for (int mi = 0; mi < 4; ++mi) {
#pragma unroll
      for (int j = 0; j < 4; ++j) {
        int r = (wm << 6) + (mi << 4) + laneRow4 + j;
        int m = posStart + r;
        int mc = m < segEnd ? m : segEnd - 1;
        float w = 1.0f;
        if constexpr (SCALE) w = row_w[mc];
#pragma unroll
        for (int ni = 0; ni < 4; ++ni) {
          int cl = (wn << 6) + (ni << 4) + laneCol;
          float v = acc[mi][ni][j] + (split == 0 ? biasE[(nt << 7) + cl] : 0.0f);
          if constexpr (GELU) v = gelu_tanh(v);
          if constexpr (SCALE) v *= w;
          Cs[r * 136 + cl] = f2bf(v);
        }
      }
    }
    __syncthreads();
    int r0 = tid >> 4, q = tid & 15;
    u16* OutU = (u16*)Out + (size_t)split * pstride;
#pragma unroll
    for (int i = 0; i < 8; ++i) {
      int r = (i << 4) + r0;
      if (posStart + r < segEnd)
        *((uint4*)(OutU + (size_t)(posStart + r) * NFULL + (nt << 7)) + q) =
            ((uint4*)(Cs + (size_t)r * 136))[q];
    }
  } else {
    float* OutF = (float*)Out + (size_t)split * pstride;
#pragma unroll
    for (int mi = 0; mi < 4; ++mi) {
#pragma unroll
      for (int j = 0; j < 4; ++j) {
        int m = posStart + (wm << 6) + (mi << 4) + laneRow4 + j;
        if (m < segEnd) {
          float w = 1.0f;
          if constexpr (SCALE) w = row_w[m];
#pragma unroll
          for (int ni = 0; ni < 4; ++ni) {
            int n = (nt << 7) + (wn << 6) + (ni << 4) + laneCol;
            float v = acc[mi][ni][j] + (split == 0 ? biasE[n] : 0.0f);
            OutF[(size_t)m * NFULL + n] = v * w;
          }
        }
      }
    }
  }
}

// ---------- combine: out[tok] = sum over splits x {pos0,pos1} of bf16 partials
template <int NSPLIT>
__global__ void k_combine(const u16* __restrict__ P, size_t pstride,
                          const int* __restrict__ pos_of, float* __restrict__ out, int Ntok) {
  int tok = (blockIdx.x << 2) + (threadIdx.x >> 6);
  int lane = threadIdx.x & 63;
  if (tok >= Ntok) return;
  int p0 = pos_of[tok * 2], p1 = pos_of[tok * 2 + 1];
  float s[8] = {};
#pragma unroll
  for (int sp = 0; sp < NSPLIT; ++sp) {
    bf16x8 a = ((const bf16x8*)(P + sp * pstride + (size_t)p0 * DM))[lane];
    bf16x8 b = ((const bf16x8*)(P + sp * pstride + (size_t)p1 * DM))[lane];
#pragma unroll
    for (int i = 0; i < 8; ++i) s[i] += (float)a[i] + (float)b[i];
  }
  float4* o = (float4*)(out + (size_t)tok * DM + lane * 8);
  o[0] = make_float4(s[0], s[1], s[2], s[3]);
  o[1] = make_float4(s[4], s[5], s[6], s[7]);
}

extern "C" void kernel_launch(void* const* d_in, const int* in_sizes, int n_in,
                              void* d_out, int out_size, void* d_ws, size_t ws_size,
                              hipStream_t stream) {
  const float* x  = (const float*)d_in[0];
  const float* Wr = (const float*)d_in[1];
  const float* br = (const float*)d_in[2];
  const float* W1 = (const float*)d_in[3];
  const float* b1 = (const float*)d_in[4];
  const float* W2 = (const float*)d_in[5];
  const float* b2 = (const float*)d_in[6];
  float* out = (float*)d_out;

  int Ntok = in_sizes[0] / DM;          // 4096
  int npairs = Ntok * 2;                // 8192
  int maxmt = npairs / 128 + NEXP;      // 72
  size_t pstride = (size_t)npairs * DM; // u16 elems per split

  char* p = (char*)d_ws;
  u16* W1T = (u16*)p;  p += (size_t)NEXP * DFF * DM * 2;
  u16* W2T = (u16*)p;  p += (size_t)NEXP * DM * DFF * 2;
  u16* Xb  = (u16*)p;  p += (size_t)Ntok * DM * 2;
  u16* H   = (u16*)p;  p += (size_t)npairs * DFF * 2;
  u16* Part = (u16*)p; p += 2 * pstride * 2;          // [2][npairs][DM] bf16
  int* sel_idx   = (int*)p;   p += (size_t)npairs * 4;
  float* sel_w   = (float*)p; p += (size_t)npairs * 4;
  int* pos_of    = (int*)p;   p += (size_t)npairs * 4;
  int* row_token = (int*)p;   p += (size_t)npairs * 4;
  float* row_w   = (float*)p; p += (size_t)npairs * 4;
  int* tileMeta  = (int*)p;   p += (size_t)(maxmt * 3 + 16) * 4;
  int* gMeta     = (int*)p;   p += 64;

  k_prep<<<dim3(5120 + Ntok / 4), 256, 0, stream>>>(W1, W1T, W2, W2T, x, Xb, Wr, br,
                                                    sel_idx, sel_w, Ntok);
  k_scatter<<<dim3(NEXP), 1024, 0, stream>>>(sel_idx, sel_w, npairs, row_token, row_w,
                                             pos_of, tileMeta, gMeta);
  // GEMM1: H[pos][2048] = gelu(Xb[row_token[pos]] * W1T + b1)  (A via rowMap)
  k_gemm<DFF, DM, DM, true, false, true, true>
      <<<dim3(maxmt * (DFF / 128)), 256, 0, stream>>>(
          Xb, row_token, W1T, b1, nullptr, H, 0, tileMeta, gMeta, maxmt);
  // GEMM2: bf16 partials, split-K=2, bias on split0, row_w scale, LDS epilogue
  k_gemm<DM, DFF, DFF / 2, false, true, true, false>
      <<<dim3(maxmt * (DM / 128) * 2), 256, 0, stream>>>(
          H, nullptr, W2T, b2, row_w, Part, pstride, tileMeta, gMeta, maxmt);
  k_combine<2><<<dim3(Ntok / 4), 256, 0, stream>>>(Part, pstride, pos_of, out, Ntok);
}

// Round 15
// 127.736 us; speedup vs baseline: 1.4307x; 1.0388x over previous
//
#include <hip/hip_runtime.h>
#include <hip/hip_bf16.h>
#include <cstdint>

typedef unsigned short u16;
typedef __bf16 bf16_t;
typedef __bf16 bf16x8 __attribute__((ext_vector_type(8)));
typedef float f32x4 __attribute__((ext_vector_type(4)));

#define DM   512
#define DFF  2048
#define NEXP 8

__device__ __forceinline__ u16 f2bf(float f) {
  bf16_t b = (bf16_t)f;
  return __builtin_bit_cast(u16, b);
}
__device__ __forceinline__ uint32_t pack_bf2(float lo, float hi) {
  return (uint32_t)f2bf(lo) | ((uint32_t)f2bf(hi) << 16);
}
__device__ __forceinline__ float gelu_tanh(float x) {
  float x3 = x * x * x;
  float z = 0.7978845608028654f * (x + 0.044715f * x3);
  float az = fabsf(z);
  float e = __expf(2.0f * az);
  float t = 1.0f - 2.0f / (e + 1.0f);
  t = copysignf(t, z);
  return 0.5f * x * (1.0f + t);
}
__device__ __forceinline__ void async16(const u16* g, u16* l) {
  __builtin_amdgcn_global_load_lds((const __attribute__((address_space(1))) void*)g,
                                   (__attribute__((address_space(3))) void*)l, 16, 0, 0);
}

// ---------- transpose tile body: src [R][C] f32 -> dst [C][R] bf16 (16B stores)
__device__ __forceinline__ void transpose_tile(const float* __restrict__ s,
                                               u16* __restrict__ d, int R, int C,
                                               int tileIdx) {
  __shared__ u16 tile[64][66];
  int tilesC = C >> 6;
  int bR = (tileIdx / tilesC) << 6;
  int bC = (tileIdx % tilesC) << 6;
  int rr = threadIdx.x >> 4;
  int cc = (threadIdx.x & 15) << 2;
#pragma unroll
  for (int i = 0; i < 4; ++i) {
    int r = (i << 4) + rr;
    float4 v = *(const float4*)(s + (size_t)(bR + r) * C + bC + cc);
    *(uint32_t*)&tile[r][cc]     = pack_bf2(v.x, v.y);
    *(uint32_t*)&tile[r][cc + 2] = pack_bf2(v.z, v.w);
  }
  __syncthreads();
  int c  = threadIdx.x >> 3;          // 0..31
  int j0 = (threadIdx.x & 7) << 3;    // 0,8,...,56
#pragma unroll
  for (int half = 0; half < 2; ++half) {
    int cc2 = c + (half << 5);
    uint32_t w0 = (uint32_t)tile[j0 + 0][cc2] | ((uint32_t)tile[j0 + 1][cc2] << 16);
    uint32_t w1 = (uint32_t)tile[j0 + 2][cc2] | ((uint32_t)tile[j0 + 3][cc2] << 16);
    uint32_t w2 = (uint32_t)tile[j0 + 4][cc2] | ((uint32_t)tile[j0 + 5][cc2] << 16);
    uint32_t w3 = (uint32_t)tile[j0 + 6][cc2] | ((uint32_t)tile[j0 + 7][cc2] << 16);
    *(uint4*)(&d[(size_t)(bC + cc2) * R + bR + j0]) = make_uint4(w0, w1, w2, w3);
  }
}

// ---------- fused prep: W1 transpose | W2 transpose | x->bf16 | router
__global__ void k_prep(const float* __restrict__ W1, u16* __restrict__ W1T,
                       const float* __restrict__ W2, u16* __restrict__ W2T,
                       const float* __restrict__ x, u16* __restrict__ Xb,
                       const float* __restrict__ Wr, const float* __restrict__ br,
                       int* __restrict__ sel_idx, float* __restrict__ sel_w, int Ntok) {
  int b = blockIdx.x;
  if (b < 2048) {
    int e = b >> 8, t = b & 255;
    transpose_tile(W1 + (size_t)e * DM * DFF, W1T + (size_t)e * DM * DFF, DM, DFF, t);
    return;
  }
  if (b < 4096) {
    int e = (b - 2048) >> 8, t = (b - 2048) & 255;
    transpose_tile(W2 + (size_t)e * DFF * DM, W2T + (size_t)e * DFF * DM, DFF, DM, t);
    return;
  }
  if (b < 5120) {
    size_t base = ((size_t)(b - 4096) << 11) + ((size_t)threadIdx.x << 3);
    float4 a = *(const float4*)(x + base);
    float4 c = *(const float4*)(x + base + 4);
    uint4 o;
    o.x = pack_bf2(a.x, a.y);
    o.y = pack_bf2(a.z, a.w);
    o.z = pack_bf2(c.x, c.y);
    o.w = pack_bf2(c.z, c.w);
    *(uint4*)(Xb + base) = o;
    return;
  }
  int rb = b - 5120;
  int wid = threadIdx.x >> 6;
  int lane = threadIdx.x & 63;
  int tok = (rb << 2) + wid;
  if (tok >= Ntok) return;
  const float4* xr = (const float4*)(x + (size_t)tok * DM);
  float4 x0 = xr[lane * 2], x1 = xr[lane * 2 + 1];
  float logit[NEXP];
#pragma unroll
  for (int e = 0; e < NEXP; ++e) {
    const float4* wr = (const float4*)(Wr + e * DM);
    float4 w0 = wr[lane * 2], w1 = wr[lane * 2 + 1];
    float p = x0.x * w0.x + x0.y * w0.y + x0.z * w0.z + x0.w * w0.w
            + x1.x * w1.x + x1.y * w1.y + x1.z * w1.z + x1.w * w1.w;
#pragma unroll
    for (int off = 32; off; off >>= 1) p += __shfl_xor(p, off, 64);
    logit[e] = p + br[e];
  }
  if (lane == 0) {
    float mx = logit[0];
#pragma unroll
    for (int e = 1; e < NEXP; ++e) mx = fmaxf(mx, logit[e]);
    float pr[NEXP];
#pragma unroll
    for (int e = 0; e < NEXP; ++e) pr[e] = __expf(logit[e] - mx);
    int i0 = 0;
#pragma unroll
    for (int e = 1; e < NEXP; ++e) if (pr[e] > pr[i0]) i0 = e;
    int i1 = -1;
#pragma unroll
    for (int e = 0; e < NEXP; ++e) {
      if (e == i0) continue;
      if (i1 < 0 || pr[e] > pr[i1]) i1 = e;
    }
    float s2 = pr[i0] + pr[i1];
    sel_idx[tok * 2]     = i0;
    sel_idx[tok * 2 + 1] = i1;
    sel_w[tok * 2]       = pr[i0] / s2;
    sel_w[tok * 2 + 1]   = pr[i1] / s2;
  }
}

// ---------- scatter: 8 blocks, one expert each; block 0 also writes tileMeta.
__global__ void k_scatter(const int* __restrict__ sel_idx, const float* __restrict__ sel_w,
                          int npairs, int* __restrict__ row_token, float* __restrict__ row_w,
                          int* __restrict__ pos_of, int* __restrict__ tileMeta,
                          int* __restrict__ gMeta) {
  __shared__ int cnt[NEXP], offs[NEXP], cur;
  int eb = blockIdx.x;          // expert this block assigns
  int tid = threadIdx.x;
  int lane = tid & 63;
  if (tid < NEXP) cnt[tid] = 0;
  if (tid == 0) cur = 0;
  __syncthreads();
  for (int p = tid; p < npairs; p += blockDim.x) {
    int e = sel_idx[p];
#pragma unroll
    for (int ex = 0; ex < NEXP; ++ex) {
      unsigned long long m = __ballot(e == ex);
      if (lane == 0 && m) atomicAdd(&cnt[ex], __popcll(m));
    }
  }
  __syncthreads();
  if (tid == 0) {
    int o = 0;
    for (int e = 0; e < NEXP; ++e) { offs[e] = o; o += cnt[e]; }
    if (eb == 0) {
      int nmt = 0;
      for (int e = 0; e < NEXP; ++e) {
        int c = cnt[e];
        int nt = (c + 127) >> 7;
        for (int t = 0; t < nt; ++t) {
          tileMeta[nmt * 3 + 0] = offs[e] + t * 128;
          tileMeta[nmt * 3 + 1] = offs[e] + c;
          tileMeta[nmt * 3 + 2] = e;
          ++nmt;
        }
      }
      gMeta[0] = nmt;
    }
  }
  __syncthreads();
  for (int p = tid; p < npairs; p += blockDim.x) {
    int e = sel_idx[p];
    unsigned long long m = __ballot(e == eb);
    if (m) {
      int leader = __ffsll((long long)m) - 1;
      int base = 0;
      if (lane == leader) base = atomicAdd(&cur, __popcll(m));
      base = __shfl(base, leader, 64);
      if (e == eb) {
        int pos = offs[eb] + base + __popcll(m & ((1ull << lane) - 1ull));
        row_token[pos] = p >> 1;
        row_w[pos] = sel_w[p];
        pos_of[p] = pos;
      }
    }
  }
}

// ---------- grouped GEMM (R3-proven core): 128x128, BK=32, 3-slot ring,
// counted vmcnt(4), 1 barrier/K-tile, 256 thr / 4 waves (2x2), 48KB -> 3 blocks/CU.
// NSPLIT template: split is COMPILE-TIME 0 when NSPLIT==1 (restores R13 codegen).
template <int NFULL, int KTOT, int KCHUNK, int NSPLIT, bool GELU, bool SCALE,
          bool OUTBF16, bool USEMAP>
__launch_bounds__(256)
__global__ void k_gemm(const u16* __restrict__ A, const int* __restrict__ rowMap,
                       const u16* __restrict__ BT,
                       const float* __restrict__ bias, const float* __restrict__ row_w,
                       void* __restrict__ Out, size_t pstride,
                       const int* __restrict__ tileMeta, const int* __restrict__ gMeta,
                       int maxmt) {
  constexpr int NT = NFULL / 128;
  constexpr int NK = KCHUNK / 32;
  int NB = gridDim.x;
  int bid = blockIdx.x;
  int wg = ((NB & 7) == 0) ? ((bid & 7) * (NB >> 3) + (bid >> 3)) : bid;  // XCD chunking
  int nt = wg % NT;                      // nt fastest -> A-tile L2 reuse within XCD
  int rem = wg / NT;
  int mt = rem % maxmt;
  int split = (NSPLIT == 1) ? 0 : rem / maxmt;
  if (mt >= gMeta[0]) return;
  int posStart = tileMeta[mt * 3 + 0];
  int segEnd   = tileMeta[mt * 3 + 1];
  int e        = tileMeta[mt * 3 + 2];

  __shared__ __align__(16) u16 smem[24576];

  int tid = threadIdx.x, lane = tid & 63, wid = tid >> 6;
  int wm = wid >> 1, wn = wid & 1;

  const u16* Abase = A + (size_t)split * KCHUNK;
  const u16* Bbase = BT + ((size_t)e * NFULL + (size_t)nt * 128) * KTOT + (size_t)split * KCHUNK;

  int l4 = lane >> 2, c4 = lane & 3;
  const u16* aS[2];
  const u16* bS[2];
#pragma unroll
  for (int i = 0; i < 2; ++i) {
    int r = i * 64 + wid * 16 + l4;
    int gra = posStart + r;
    if (gra >= segEnd) gra = segEnd - 1;
    if constexpr (USEMAP) gra = rowMap[gra];
    int cs = c4 ^ ((r >> 1) & 3);
    aS[i] = Abase + (size_t)gra * KTOT + cs * 8;
    bS[i] = Bbase + (size_t)r * KTOT + cs * 8;
  }

  auto stage = [&](int kt, int buf) {
    u16* as = smem + buf * 8192;
    u16* bs = as + 4096;
#pragma unroll
    for (int i = 0; i < 2; ++i) {
      async16(aS[i] + kt * 32, as + i * 2048 + wid * 512);
      async16(bS[i] + kt * 32, bs + i * 2048 + wid * 512);
    }
  };

  f32x4 acc[4][4] = {};

  stage(0, 0);
  stage(1, 1);
  int bufC = 0, bufS = 2;
#pragma unroll 1
  for (int t = 0; t < NK; ++t) {
    if (t + 1 < NK) asm volatile("s_waitcnt vmcnt(4)" ::: "memory");
    else            asm volatile("s_waitcnt vmcnt(0)" ::: "memory");
    __builtin_amdgcn_s_barrier();
    asm volatile("" ::: "memory");
    if (t + 2 < NK) { stage(t + 2, bufS); bufS = (bufS == 2) ? 0 : bufS + 1; }
    const char* AsB = (const char*)(smem + bufC * 8192);
    const char* BsB = AsB + 8192;
    int kb = (lane >> 4) << 4;
    bf16x8 av[4], bv[4];
#pragma unroll
    for (int mi = 0; mi < 4; ++mi) {
      int row = (wm << 6) + (mi << 4) + (lane & 15);
      av[mi] = *(const bf16x8*)(AsB + row * 64 + (kb ^ (((row >> 1) & 3) << 4)));
    }
#pragma unroll
    for (int ni = 0; ni < 4; ++ni) {
      int row = (wn << 6) + (ni << 4) + (lane & 15);
      bv[ni] = *(const bf16x8*)(BsB + row * 64 + (kb ^ (((row >> 1) & 3) << 4)));
    }
    __builtin_amdgcn_s_setprio(1);
#pragma unroll
    for (int mi = 0; mi < 4; ++mi)
#pragma unroll
      for (int ni = 0; ni < 4; ++ni)
        acc[mi][ni] = __builtin_amdgcn_mfma_f32_16x16x32_bf16(av[mi], bv[ni], acc[mi][ni], 0, 0, 0);
    __builtin_amdgcn_s_setprio(0);
    bufC = (bufC == 2) ? 0 : bufC + 1;
  }

  int laneCol = lane & 15;
  int laneRow4 = (lane >> 4) << 2;
  const float* biasE = bias + (size_t)e * NFULL;

  if constexpr (OUTBF16) {
    __syncthreads();
    u16* Cs = smem;   // 128 x 136 u16 = 34KB
#pragma unroll
    for (int mi = 0; mi < 4; ++mi) {
#pragma unroll
      for (int j = 0; j < 4; ++j) {
        int r = (wm << 6) + (mi << 4) + laneRow4 + j;
        int m = posStart + r;
        int mc = m < segEnd ? m : segEnd - 1;
        float w = 1.0f;
        if constexpr (SCALE) w = row_w[mc];
#pragma unroll
        for (int ni = 0; ni < 4; ++ni) {
          int cl = (wn << 6) + (ni << 4) + laneCol;
          float v = acc[mi][ni][j] + (split == 0 ? biasE[(nt << 7) + cl] : 0.0f);
          if constexpr (GELU) v = gelu_tanh(v);
          if constexpr (SCALE) v *= w;
          Cs[r * 136 + cl] = f2bf(v);
        }
      }
    }
    __syncthreads();
    int r0 = tid >> 4, q = tid & 15;
    u16* OutU = (u16*)Out + (size_t)split * pstride;
#pragma unroll
    for (int i = 0; i < 8; ++i) {
      int r = (i << 4) + r0;
      if (posStart + r < segEnd)
        *((uint4*)(OutU + (size_t)(posStart + r) * NFULL + (nt << 7)) + q) =
            ((uint4*)(Cs + (size_t)r * 136))[q];
    }
  } else {
    float* OutF = (float*)Out + (size_t)split * pstride;
#pragma unroll
    for (int mi = 0; mi < 4; ++mi) {
#pragma unroll
      for (int j = 0; j < 4; ++j) {
        int m = posStart + (wm << 6) + (mi << 4) + laneRow4 + j;
        if (m < segEnd) {
          float w = 1.0f;
          if constexpr (SCALE) w = row_w[m];
#pragma unroll
          for (int ni = 0; ni < 4; ++ni) {
            int n = (nt << 7) + (wn << 6) + (ni << 4) + laneCol;
            float v = acc[mi][ni][j] + (split == 0 ? biasE[n] : 0.0f);
            OutF[(size_t)m * NFULL + n] = v * w;
          }
        }
      }
    }
  }
}

// ---------- combine: out[tok] = sum over splits x {pos0,pos1} of bf16 partials
template <int NSPLIT>
__global__ void k_combine(const u16* __restrict__ P, size_t pstride,
                          const int* __restrict__ pos_of, float* __restrict__ out, int Ntok) {
  int tok = (blockIdx.x << 2) + (threadIdx.x >> 6);
  int lane = threadIdx.x & 63;
  if (tok >= Ntok) return;
  int p0 = pos_of[tok * 2], p1 = pos_of[tok * 2 + 1];
  float s[8] = {};
#pragma unroll
  for (int sp = 0; sp < NSPLIT; ++sp) {
    bf16x8 a = ((const bf16x8*)(P + sp * pstride + (size_t)p0 * DM))[lane];
    bf16x8 b = ((const bf16x8*)(P + sp * pstride + (size_t)p1 * DM))[lane];
#pragma unroll
    for (int i = 0; i < 8; ++i) s[i] += (float)a[i] + (float)b[i];
  }
  float4* o = (float4*)(out + (size_t)tok * DM + lane * 8);
  o[0] = make_float4(s[0], s[1], s[2], s[3]);
  o[1] = make_float4(s[4], s[5], s[6], s[7]);
}

extern "C" void kernel_launch(void* const* d_in, const int* in_sizes, int n_in,
                              void* d_out, int out_size, void* d_ws, size_t ws_size,
                              hipStream_t stream) {
  const float* x  = (const float*)d_in[0];
  const float* Wr = (const float*)d_in[1];
  const float* br = (const float*)d_in[2];
  const float* W1 = (const float*)d_in[3];
  const float* b1 = (const float*)d_in[4];
  const float* W2 = (const float*)d_in[5];
  const float* b2 = (const float*)d_in[6];
  float* out = (float*)d_out;

  int Ntok = in_sizes[0] / DM;          // 4096
  int npairs = Ntok * 2;                // 8192
  int maxmt = npairs / 128 + NEXP;      // 72
  size_t pstride = (size_t)npairs * DM; // u16 elems per split

  char* p = (char*)d_ws;
  u16* W1T = (u16*)p;  p += (size_t)NEXP * DFF * DM * 2;
  u16* W2T = (u16*)p;  p += (size_t)NEXP * DM * DFF * 2;
  u16* Xb  = (u16*)p;  p += (size_t)Ntok * DM * 2;
  u16* H   = (u16*)p;  p += (size_t)npairs * DFF * 2;
  u16* Part = (u16*)p; p += 2 * pstride * 2;          // [2][npairs][DM] bf16
  int* sel_idx   = (int*)p;   p += (size_t)npairs * 4;
  float* sel_w   = (float*)p; p += (size_t)npairs * 4;
  int* pos_of    = (int*)p;   p += (size_t)npairs * 4;
  int* row_token = (int*)p;   p += (size_t)npairs * 4;
  float* row_w   = (float*)p; p += (size_t)npairs * 4;
  int* tileMeta  = (int*)p;   p += (size_t)(maxmt * 3 + 16) * 4;
  int* gMeta     = (int*)p;   p += 64;

  k_prep<<<dim3(5120 + Ntok / 4), 256, 0, stream>>>(W1, W1T, W2, W2T, x, Xb, Wr, br,
                                                    sel_idx, sel_w, Ntok);
  k_scatter<<<dim3(NEXP), 1024, 0, stream>>>(sel_idx, sel_w, npairs, row_token, row_w,
                                             pos_of, tileMeta, gMeta);
  // GEMM1: H[pos][2048] = gelu(Xb[row_token[pos]] * W1T + b1)  (split compile-time 0)
  k_gemm<DFF, DM, DM, 1, true, false, true, true>
      <<<dim3(maxmt * (DFF / 128)), 256, 0, stream>>>(
          Xb, row_token, W1T, b1, nullptr, H, 0, tileMeta, gMeta, maxmt);
  // GEMM2: bf16 partials, split-K=2, bias on split0, row_w scale, LDS epilogue
  k_gemm<DM, DFF, DFF / 2, 2, false, true, true, false>
      <<<dim3(maxmt * (DM / 128) * 2), 256, 0, stream>>>(
          H, nullptr, W2T, b2, row_w, Part, pstride, tileMeta, gMeta, maxmt);
  k_combine<2><<<dim3(Ntok / 4), 256, 0, stream>>>(Part, pstride, pos_of, out, Ntok);
}

// Round 16
// 123.817 us; speedup vs baseline: 1.4760x; 1.0317x over previous
//
#include <hip/hip_runtime.h>
#include <hip/hip_bf16.h>
#include <cstdint>

typedef unsigned short u16;
typedef __bf16 bf16_t;
typedef __bf16 bf16x8 __attribute__((ext_vector_type(8)));
typedef float f32x4 __attribute__((ext_vector_type(4)));

#define DM   512
#define DFF  2048
#define NEXP 8

__device__ __forceinline__ u16 f2bf(float f) {
  bf16_t b = (bf16_t)f;
  return __builtin_bit_cast(u16, b);
}
__device__ __forceinline__ uint32_t pack_bf2(float lo, float hi) {
  return (uint32_t)f2bf(lo) | ((uint32_t)f2bf(hi) << 16);
}
__device__ __forceinline__ float gelu_tanh(float x) {
  float x3 = x * x * x;
  float z = 0.7978845608028654f * (x + 0.044715f * x3);
  float az = fabsf(z);
  float e = __expf(2.0f * az);
  float t = 1.0f - 2.0f / (e + 1.0f);
  t = copysignf(t, z);
  return 0.5f * x * (1.0f + t);
}
__device__ __forceinline__ void async16(const u16* g, u16* l) {
  __builtin_amdgcn_global_load_lds((const __attribute__((address_space(1))) void*)g,
                                   (__attribute__((address_space(3))) void*)l, 16, 0, 0);
}

// ---------- transpose tile body: src [R][C] f32 -> dst [C][R] bf16 (16B stores)
__device__ __forceinline__ void transpose_tile(const float* __restrict__ s,
                                               u16* __restrict__ d, int R, int C,
                                               int tileIdx) {
  __shared__ u16 tile[64][66];
  int tilesC = C >> 6;
  int bR = (tileIdx / tilesC) << 6;
  int bC = (tileIdx % tilesC) << 6;
  int rr = threadIdx.x >> 4;
  int cc = (threadIdx.x & 15) << 2;
#pragma unroll
  for (int i = 0; i < 4; ++i) {
    int r = (i << 4) + rr;
    float4 v = *(const float4*)(s + (size_t)(bR + r) * C + bC + cc);
    *(uint32_t*)&tile[r][cc]     = pack_bf2(v.x, v.y);
    *(uint32_t*)&tile[r][cc + 2] = pack_bf2(v.z, v.w);
  }
  __syncthreads();
  int c  = threadIdx.x >> 3;          // 0..31
  int j0 = (threadIdx.x & 7) << 3;    // 0,8,...,56
#pragma unroll
  for (int half = 0; half < 2; ++half) {
    int cc2 = c + (half << 5);
    uint32_t w0 = (uint32_t)tile[j0 + 0][cc2] | ((uint32_t)tile[j0 + 1][cc2] << 16);
    uint32_t w1 = (uint32_t)tile[j0 + 2][cc2] | ((uint32_t)tile[j0 + 3][cc2] << 16);
    uint32_t w2 = (uint32_t)tile[j0 + 4][cc2] | ((uint32_t)tile[j0 + 5][cc2] << 16);
    uint32_t w3 = (uint32_t)tile[j0 + 6][cc2] | ((uint32_t)tile[j0 + 7][cc2] << 16);
    *(uint4*)(&d[(size_t)(bC + cc2) * R + bR + j0]) = make_uint4(w0, w1, w2, w3);
  }
}

// ---------- fused prep: W1 transpose | W2 transpose | x->bf16 | router
__global__ void k_prep(const float* __restrict__ W1, u16* __restrict__ W1T,
                       const float* __restrict__ W2, u16* __restrict__ W2T,
                       const float* __restrict__ x, u16* __restrict__ Xb,
                       const float* __restrict__ Wr, const float* __restrict__ br,
                       int* __restrict__ sel_idx, float* __restrict__ sel_w, int Ntok) {
  int b = blockIdx.x;
  if (b < 2048) {
    int e = b >> 8, t = b & 255;
    transpose_tile(W1 + (size_t)e * DM * DFF, W1T + (size_t)e * DM * DFF, DM, DFF, t);
    return;
  }
  if (b < 4096) {
    int e = (b - 2048) >> 8, t = (b - 2048) & 255;
    transpose_tile(W2 + (size_t)e * DFF * DM, W2T + (size_t)e * DFF * DM, DFF, DM, t);
    return;
  }
  if (b < 5120) {
    size_t base = ((size_t)(b - 4096) << 11) + ((size_t)threadIdx.x << 3);
    float4 a = *(const float4*)(x + base);
    float4 c = *(const float4*)(x + base + 4);
    uint4 o;
    o.x = pack_bf2(a.x, a.y);
    o.y = pack_bf2(a.z, a.w);
    o.z = pack_bf2(c.x, c.y);
    o.w = pack_bf2(c.z, c.w);
    *(uint4*)(Xb + base) = o;
    return;
  }
  int rb = b - 5120;
  int wid = threadIdx.x >> 6;
  int lane = threadIdx.x & 63;
  int tok = (rb << 2) + wid;
  if (tok >= Ntok) return;
  const float4* xr = (const float4*)(x + (size_t)tok * DM);
  float4 x0 = xr[lane * 2], x1 = xr[lane * 2 + 1];
  float logit[NEXP];
#pragma unroll
  for (int e = 0; e < NEXP; ++e) {
    const float4* wr = (const float4*)(Wr + e * DM);
    float4 w0 = wr[lane * 2], w1 = wr[lane * 2 + 1];
    float p = x0.x * w0.x + x0.y * w0.y + x0.z * w0.z + x0.w * w0.w
            + x1.x * w1.x + x1.y * w1.y + x1.z * w1.z + x1.w * w1.w;
#pragma unroll
    for (int off = 32; off; off >>= 1) p += __shfl_xor(p, off, 64);
    logit[e] = p + br[e];
  }
  if (lane == 0) {
    float mx = logit[0];
#pragma unroll
    for (int e = 1; e < NEXP; ++e) mx = fmaxf(mx, logit[e]);
    float pr[NEXP];
#pragma unroll
    for (int e = 0; e < NEXP; ++e) pr[e] = __expf(logit[e] - mx);
    int i0 = 0;
#pragma unroll
    for (int e = 1; e < NEXP; ++e) if (pr[e] > pr[i0]) i0 = e;
    int i1 = -1;
#pragma unroll
    for (int e = 0; e < NEXP; ++e) {
      if (e == i0) continue;
      if (i1 < 0 || pr[e] > pr[i1]) i1 = e;
    }
    float s2 = pr[i0] + pr[i1];
    sel_idx[tok * 2]     = i0;
    sel_idx[tok * 2 + 1] = i1;
    sel_w[tok * 2]       = pr[i0] / s2;
    sel_w[tok * 2 + 1]   = pr[i1] / s2;
  }
}

// ---------- scatter: 8 blocks, one expert each; block 0 also writes tileMeta.
__global__ void k_scatter(const int* __restrict__ sel_idx, const float* __restrict__ sel_w,
                          int npairs, int* __restrict__ row_token, float* __restrict__ row_w,
                          int* __restrict__ pos_of, int* __restrict__ tileMeta,
                          int* __restrict__ gMeta) {
  __shared__ int cnt[NEXP], offs[NEXP], cur;
  int eb = blockIdx.x;
  int tid = threadIdx.x;
  int lane = tid & 63;
  if (tid < NEXP) cnt[tid] = 0;
  if (tid == 0) cur = 0;
  __syncthreads();
  for (int p = tid; p < npairs; p += blockDim.x) {
    int e = sel_idx[p];
#pragma unroll
    for (int ex = 0; ex < NEXP; ++ex) {
      unsigned long long m = __ballot(e == ex);
      if (lane == 0 && m) atomicAdd(&cnt[ex], __popcll(m));
    }
  }
  __syncthreads();
  if (tid == 0) {
    int o = 0;
    for (int e = 0; e < NEXP; ++e) { offs[e] = o; o += cnt[e]; }
    if (eb == 0) {
      int nmt = 0;
      for (int e = 0; e < NEXP; ++e) {
        int c = cnt[e];
        int nt = (c + 127) >> 7;
        for (int t = 0; t < nt; ++t) {
          tileMeta[nmt * 3 + 0] = offs[e] + t * 128;
          tileMeta[nmt * 3 + 1] = offs[e] + c;
          tileMeta[nmt * 3 + 2] = e;
          ++nmt;
        }
      }
      gMeta[0] = nmt;
    }
  }
  __syncthreads();
  for (int p = tid; p < npairs; p += blockDim.x) {
    int e = sel_idx[p];
    unsigned long long m = __ballot(e == eb);
    if (m) {
      int leader = __ffsll((long long)m) - 1;
      int base = 0;
      if (lane == leader) base = atomicAdd(&cur, __popcll(m));
      base = __shfl(base, leader, 64);
      if (e == eb) {
        int pos = offs[eb] + base + __popcll(m & ((1ull << lane) - 1ull));
        row_token[pos] = p >> 1;
        row_w[pos] = sel_w[p];
        pos_of[p] = pos;
      }
    }
  }
}

// ---------- grouped GEMM (R3-proven pipeline), BM=128 x BN (64 or 128), BK=32,
// 3-slot ring, counted vmcnt (one stage in flight), 1 barrier/K-tile,
// 256 thr / 4 waves (2x2). BN=64: slot 12KB -> 36KB LDS -> 4 blocks/CU.
// BN=128: slot 16KB -> 48KB -> 3 blocks/CU (R15-identical codegen).
template <int BN, int NFULL, int KTOT, int KCHUNK, int NSPLIT, bool GELU, bool SCALE,
          bool OUTBF16, bool USEMAP>
__launch_bounds__(256)
__global__ void k_gemm(const u16* __restrict__ A, const int* __restrict__ rowMap,
                       const u16* __restrict__ BT,
                       const float* __restrict__ bias, const float* __restrict__ row_w,
                       void* __restrict__ Out, size_t pstride,
                       const int* __restrict__ tileMeta, const int* __restrict__ gMeta,
                       int maxmt) {
  constexpr int NT  = NFULL / BN;
  constexpr int NK  = KCHUNK / 32;
  constexpr int NI  = BN / 32;              // bv frags per wave (wave covers BN/2 cols)
  constexpr int NBI = BN / 64;              // B staging instrs per tile
  constexpr int SLOTU = (128 + BN) * 32;    // u16 per slot (A 4096 + B BN*32)
  constexpr int LPS = 2 + NBI;              // loads per stage

  __shared__ __align__(16) u16 smem[3 * SLOTU];

  int NB = gridDim.x;
  int bid = blockIdx.x;
  int wg = ((NB & 7) == 0) ? ((bid & 7) * (NB >> 3) + (bid >> 3)) : bid;  // XCD chunking
  int nt = wg % NT;
  int rem = wg / NT;
  int mt = rem % maxmt;
  int split = (NSPLIT == 1) ? 0 : rem / maxmt;
  if (mt >= gMeta[0]) return;
  int posStart = tileMeta[mt * 3 + 0];
  int segEnd   = tileMeta[mt * 3 + 1];
  int e        = tileMeta[mt * 3 + 2];

  int tid = threadIdx.x, lane = tid & 63, wid = tid >> 6;
  int wm = wid >> 1, wn = wid & 1;

  const u16* Abase = A + (size_t)split * KCHUNK;
  const u16* Bbase = BT + ((size_t)e * NFULL + (size_t)nt * BN) * KTOT + (size_t)split * KCHUNK;

  // staging: instr covers 64 rows (64B each); src pre-swizzled chunk = c4 ^ ((r>>1)&3)
  int l4 = lane >> 2, c4 = lane & 3;
  const u16* aS[2];
  const u16* bS[NBI];
#pragma unroll
  for (int i = 0; i < 2; ++i) {
    int r = i * 64 + wid * 16 + l4;
    int gra = posStart + r;
    if (gra >= segEnd) gra = segEnd - 1;
    if constexpr (USEMAP) gra = rowMap[gra];
    int cs = c4 ^ ((r >> 1) & 3);
    aS[i] = Abase + (size_t)gra * KTOT + cs * 8;
  }
#pragma unroll
  for (int j = 0; j < NBI; ++j) {
    int r = j * 64 + wid * 16 + l4;
    int cs = c4 ^ ((r >> 1) & 3);
    bS[j] = Bbase + (size_t)r * KTOT + cs * 8;
  }

  auto stage = [&](int kt, int buf) {
    u16* as = smem + buf * SLOTU;
    u16* bs = as + 4096;
#pragma unroll
    for (int i = 0; i < 2; ++i)
      async16(aS[i] + kt * 32, as + i * 2048 + wid * 512);
#pragma unroll
    for (int j = 0; j < NBI; ++j)
      async16(bS[j] + kt * 32, bs + j * 2048 + wid * 512);
  };

  f32x4 acc[4][NI] = {};

  stage(0, 0);
  stage(1, 1);
  int bufC = 0, bufS = 2;
#pragma unroll 1
  for (int t = 0; t < NK; ++t) {
    if (t + 1 < NK) {
      if constexpr (LPS == 4) asm volatile("s_waitcnt vmcnt(4)" ::: "memory");
      else                    asm volatile("s_waitcnt vmcnt(3)" ::: "memory");
    } else {
      asm volatile("s_waitcnt vmcnt(0)" ::: "memory");
    }
    __builtin_amdgcn_s_barrier();
    asm volatile("" ::: "memory");
    if (t + 2 < NK) { stage(t + 2, bufS); bufS = (bufS == 2) ? 0 : bufS + 1; }
    const char* AsB = (const char*)(smem + bufC * SLOTU);
    const char* BsB = AsB + 8192;
    int kb = (lane >> 4) << 4;
    bf16x8 av[4], bv[NI];
#pragma unroll
    for (int mi = 0; mi < 4; ++mi) {
      int row = (wm << 6) + (mi << 4) + (lane & 15);
      av[mi] = *(const bf16x8*)(AsB + row * 64 + (kb ^ (((row >> 1) & 3) << 4)));
    }
#pragma unroll
    for (int ni = 0; ni < NI; ++ni) {
      int row = wn * (BN / 2) + (ni << 4) + (lane & 15);
      bv[ni] = *(const bf16x8*)(BsB + row * 64 + (kb ^ (((row >> 1) & 3) << 4)));
    }
    __builtin_amdgcn_s_setprio(1);
#pragma unroll
    for (int mi = 0; mi < 4; ++mi)
#pragma unroll
      for (int ni = 0; ni < NI; ++ni)
        acc[mi][ni] = __builtin_amdgcn_mfma_f32_16x16x32_bf16(av[mi], bv[ni], acc[mi][ni], 0, 0, 0);
    __builtin_amdgcn_s_setprio(0);
    bufC = (bufC == 2) ? 0 : bufC + 1;
  }

  int laneCol = lane & 15;
  int laneRow4 = (lane >> 4) << 2;
  const float* biasE = bias + (size_t)e * NFULL;

  if constexpr (OUTBF16) {
    __syncthreads();
    constexpr int PADW = BN + 8;   // u16 per Cs row (16B-aligned)
    u16* Cs = smem;                // 128 x PADW u16 <= 34KB
#pragma unroll
    for (int mi = 0; mi < 4; ++mi) {
#pragma unroll
      for (int j = 0; j < 4; ++j) {
        int r = (wm << 6) + (mi << 4) + laneRow4 + j;
        int m = posStart + r;
        int mc = m < segEnd ? m : segEnd - 1;
        float w = 1.0f;
        if constexpr (SCALE) w = row_w[mc];
#pragma unroll
        for (int ni = 0; ni < NI; ++ni) {
          int cl = wn * (BN / 2) + (ni << 4) + laneCol;
          float v = acc[mi][ni][j] + (split == 0 ? biasE[nt * BN + cl] : 0.0f);
          if constexpr (GELU) v = gelu_tanh(v);
          if constexpr (SCALE) v *= w;
          Cs[r * PADW + cl] = f2bf(v);
        }
      }
    }
    __syncthreads();
    constexpr int TPR = BN / 8;          // uint4 chunks (= threads) per row
    constexpr int RPP = 256 / TPR;       // rows per pass
    int r0 = tid / TPR, q = tid % TPR;
    u16* OutU = (u16*)Out + (size_t)split * pstride;
#pragma unroll
    for (int i = 0; i < 128 / RPP; ++i) {
      int r = i * RPP + r0;
      if (posStart + r < segEnd)
        *((uint4*)(OutU + (size_t)(posStart + r) * NFULL + nt * BN) + q) =
            ((uint4*)(Cs + (size_t)r * PADW))[q];
    }
  } else {
    float* OutF = (float*)Out + (size_t)split * pstride;
#pragma unroll
    for (int mi = 0; mi < 4; ++mi) {
#pragma unroll
      for (int j = 0; j < 4; ++j) {
        int m = posStart + (wm << 6) + (mi << 4) + laneRow4 + j;
        if (m < segEnd) {
          float w = 1.0f;
          if constexpr (SCALE) w = row_w[m];
#pragma unroll
          for (int ni = 0; ni < NI; ++ni) {
            int n = nt * BN + wn * (BN / 2) + (ni << 4) + laneCol;
            float v = acc[mi][ni][j] + (split == 0 ? biasE[n] : 0.0f);
            OutF[(size_t)m * NFULL + n] = v * w;
          }
        }
      }
    }
  }
}

// ---------- combine: out[tok] = sum over splits x {pos0,pos1} of bf16 partials
template <int NSPLIT>
__global__ void k_combine(const u16* __restrict__ P, size_t pstride,
                          const int* __restrict__ pos_of, float* __restrict__ out, int Ntok) {
  int tok = (blockIdx.x << 2) + (threadIdx.x >> 6);
  int lane = threadIdx.x & 63;
  if (tok >= Ntok) return;
  int p0 = pos_of[tok * 2], p1 = pos_of[tok * 2 + 1];
  float s[8] = {};
#pragma unroll
  for (int sp = 0; sp < NSPLIT; ++sp) {
    bf16x8 a = ((const bf16x8*)(P + sp * pstride + (size_t)p0 * DM))[lane];
    bf16x8 b = ((const bf16x8*)(P + sp * pstride + (size_t)p1 * DM))[lane];
#pragma unroll
    for (int i = 0; i < 8; ++i) s[i] += (float)a[i] + (float)b[i];
  }
  float4* o = (float4*)(out + (size_t)tok * DM + lane * 8);
  o[0] = make_float4(s[0], s[1], s[2], s[3]);
  o[1] = make_float4(s[4], s[5], s[6], s[7]);
}

extern "C" void kernel_launch(void* const* d_in, const int* in_sizes, int n_in,
                              void* d_out, int out_size, void* d_ws, size_t ws_size,
                              hipStream_t stream) {
  const float* x  = (const float*)d_in[0];
  const float* Wr = (const float*)d_in[1];
  const float* br = (const float*)d_in[2];
  const float* W1 = (const float*)d_in[3];
  const float* b1 = (const float*)d_in[4];
  const float* W2 = (const float*)d_in[5];
  const float* b2 = (const float*)d_in[6];
  float* out = (float*)d_out;

  int Ntok = in_sizes[0] / DM;          // 4096
  int npairs = Ntok * 2;                // 8192
  int maxmt = npairs / 128 + NEXP;      // 72
  size_t pstride = (size_t)npairs * DM; // u16 elems per split

  char* p = (char*)d_ws;
  u16* W1T = (u16*)p;  p += (size_t)NEXP * DFF * DM * 2;
  u16* W2T = (u16*)p;  p += (size_t)NEXP * DM * DFF * 2;
  u16* Xb  = (u16*)p;  p += (size_t)Ntok * DM * 2;
  u16* H   = (u16*)p;  p += (size_t)npairs * DFF * 2;
  u16* Part = (u16*)p; p += 2 * pstride * 2;          // [2][npairs][DM] bf16
  int* sel_idx   = (int*)p;   p += (size_t)npairs * 4;
  float* sel_w   = (float*)p; p += (size_t)npairs * 4;
  int* pos_of    = (int*)p;   p += (size_t)npairs * 4;
  int* row_token = (int*)p;   p += (size_t)npairs * 4;
  float* row_w   = (float*)p; p += (size_t)npairs * 4;
  int* tileMeta  = (int*)p;   p += (size_t)(maxmt * 3 + 16) * 4;
  int* gMeta     = (int*)p;   p += 64;

  k_prep<<<dim3(5120 + Ntok / 4), 256, 0, stream>>>(W1, W1T, W2, W2T, x, Xb, Wr, br,
                                                    sel_idx, sel_w, Ntok);
  k_scatter<<<dim3(NEXP), 1024, 0, stream>>>(sel_idx, sel_w, npairs, row_token, row_w,
                                             pos_of, tileMeta, gMeta);
  // GEMM1: BN=64 -> 36KB LDS -> 4 blocks/CU (occupancy-law experiment), grid 72*32
  k_gemm<64, DFF, DM, DM, 1, true, false, true, true>
      <<<dim3(maxmt * (DFF / 64)), 256, 0, stream>>>(
          Xb, row_token, W1T, b1, nullptr, H, 0, tileMeta, gMeta, maxmt);
  // GEMM2: BN=128 (R15-proven), bf16 partials, split-K=2, grid 72*4*2
  k_gemm<128, DM, DFF, DFF / 2, 2, false, true, true, false>
      <<<dim3(maxmt * (DM / 128) * 2), 256, 0, stream>>>(
          H, nullptr, W2T, b2, row_w, Part, pstride, tileMeta, gMeta, maxmt);
  k_combine<2><<<dim3(Ntok / 4), 256, 0, stream>>>(Part, pstride, pos_of, out, Ntok);
}